// Round 2
// baseline (885.654 us; speedup 1.0000x reference)
//
#include <hip/hip_runtime.h>
#include <hip/hip_bf16.h>
#include <math.h>

// Problem constants
#define BB 8
#define CC 384
#define HH 14
#define WW 14
#define NHEADS 12
#define HCHAN 32
#define RH 7
#define RW 7
#define NN 196    // H*W
#define SS 49     // rH*rW
#define KKK 9
#define SK 58     // SS + KKK
#define TH 27     // 2H-1

typedef __hip_bfloat16 bf16;

__device__ __forceinline__ float bf2f(bf16 v){ return __bfloat162float(v); }
__device__ __forceinline__ float geluf(float x){ return 0.5f*x*(1.0f+erff(x*0.7071067811865475f)); }

__constant__ float c_offm[9][2] = {{0,-1},{-1,-1},{-1,0},{-1,1},{0,1},{1,1},{1,0},{1,-1},{0,0}};

// ---------------- transpose B,C,H,W (f32) -> B,H,W,C (f32) ----------------
__global__ void k_transpose(const float* __restrict__ x, float* __restrict__ xh){
  int i = blockIdx.x*256 + threadIdx.x;
  if (i >= BB*HH*WW*CC) return;
  int c = i % CC; int p = i / CC;
  int xx = p % WW; p /= WW;
  int y = p % HH; int b = p / HH;
  xh[i] = x[((b*CC + c)*HH + y)*WW + xx];
}

// ---------------- generic GEMM: C[m,o] = act(A[m,:]·Wt[o,:] + bias[o]) ------
// A: f32 [M,384] (ws), Wt: f32 [384,384] row-major (o-major), K=O=384.
// OUTMODE 0: f32 ws [M,384]; OUTMODE 1: f32 d_out at [(b*C+o)*N + n]
template<int ACT, int OUTMODE>
__global__ void __launch_bounds__(256) k_gemm(const float* __restrict__ A,
                       const float* __restrict__ Wt, const float* __restrict__ bias,
                       float* __restrict__ Co, float* __restrict__ Cb, int M){
  __shared__ float As[32][33];
  __shared__ float Ws[32][33];
  int m0 = blockIdx.x*32, o0 = blockIdx.y*32;
  int tx = threadIdx.x & 15, ty = threadIdx.x >> 4;
  float acc00=0.f, acc01=0.f, acc10=0.f, acc11=0.f;
  for (int k0 = 0; k0 < CC; k0 += 32){
    for (int l = threadIdx.x; l < 1024; l += 256){
      int r = l >> 5, cc = l & 31;
      int m = m0 + r;
      As[r][cc] = (m < M) ? A[m*CC + k0 + cc] : 0.f;
      Ws[r][cc] = Wt[(o0 + r)*CC + k0 + cc];
    }
    __syncthreads();
    #pragma unroll
    for (int kk = 0; kk < 32; ++kk){
      float a0 = As[ty*2][kk],   a1 = As[ty*2+1][kk];
      float w0 = Ws[tx*2][kk],   w1 = Ws[tx*2+1][kk];
      acc00 += a0*w0; acc01 += a0*w1; acc10 += a1*w0; acc11 += a1*w1;
    }
    __syncthreads();
  }
  float accs[2][2] = {{acc00,acc01},{acc10,acc11}};
  #pragma unroll
  for (int i = 0; i < 2; ++i)
  #pragma unroll
  for (int j = 0; j < 2; ++j){
    int m = m0 + ty*2 + i, o = o0 + tx*2 + j;
    if (m >= M) continue;
    float v = accs[i][j] + bias[o];
    if (ACT == 1) v = geluf(v);
    if (OUTMODE == 0) Co[m*CC + o] = v;
    else {
      int b = m / NN, n = m % NN;
      Cb[(b*CC + o)*NN + n] = v;
    }
  }
}

// ---------------- depthwise 3x3 stride-2 conv + LayerNorm + GELU -----------
__global__ void __launch_bounds__(384) k_dwln(const float* __restrict__ t1,
      const float* __restrict__ Wdw, const float* __restrict__ bdw,
      const float* __restrict__ lng, const float* __restrict__ lnb,
      float* __restrict__ t2){
  int blk = blockIdx.x;
  int ow = blk % RW; int oh = (blk / RW) % RH; int b = blk / (RH*RW);
  int c = threadIdx.x;
  float acc = bdw[c];
  #pragma unroll
  for (int kh = 0; kh < 3; ++kh){
    int ih = oh*2 - 1 + kh;
    if (ih < 0 || ih >= HH) continue;
    #pragma unroll
    for (int kw = 0; kw < 3; ++kw){
      int iw = ow*2 - 1 + kw;
      if (iw < 0 || iw >= WW) continue;
      acc += t1[((b*HH + ih)*WW + iw)*CC + c] * Wdw[c*9 + kh*3 + kw];
    }
  }
  __shared__ float red[6];
  __shared__ float s_mu, s_rv;
  float v = acc;
  #pragma unroll
  for (int o = 32; o > 0; o >>= 1) v += __shfl_down(v, o);
  int wid = c >> 6, lane = c & 63;
  if (lane == 0) red[wid] = v;
  __syncthreads();
  if (c == 0){ float s = 0.f; for (int i = 0; i < 6; ++i) s += red[i]; s_mu = s / CC; }
  __syncthreads();
  float mu = s_mu;
  float d = acc - mu;
  v = d*d;
  #pragma unroll
  for (int o = 32; o > 0; o >>= 1) v += __shfl_down(v, o);
  if (lane == 0) red[wid] = v;
  __syncthreads();
  if (c == 0){ float s = 0.f; for (int i = 0; i < 6; ++i) s += red[i]; s_rv = rsqrtf(s / CC + 1e-5f); }
  __syncthreads();
  float val = d * s_rv * lng[c] + lnb[c];
  t2[blk*CC + c] = geluf(val);
}

// ---------------- offset head: off[b,n,s,{y,x}] = tanh(t2·Wo2)·(1/14)·2 ----
__global__ void __launch_bounds__(256) k_off(const float* __restrict__ t2,
      const float* __restrict__ Wo2, float* __restrict__ off){
  int blk = blockIdx.x;                // b*SS + s
  int s = blk % SS; int b = blk / SS;
  __shared__ float row[CC];
  for (int c = threadIdx.x; c < CC; c += 256) row[c] = t2[blk*CC + c];
  __syncthreads();
  for (int j = threadIdx.x; j < 2*NN; j += 256){
    float acc = 0.f;
    const float* wr = Wo2 + j*CC;
    for (int c = 0; c < CC; ++c) acc += row[c]*wr[c];
    int g = j / NN, n = j % NN;
    float range = (g == 0) ? (1.0f/HH) : (1.0f/WW);
    off[((b*NN + n)*SS + s)*2 + g] = tanhf(acc) * range * 2.0f;
  }
}

// ---------------- fused per-token attention --------------------------------
__global__ void __launch_bounds__(256) k_fused(
    const float* __restrict__ xh, const float* __restrict__ q, const float* __restrict__ off,
    const float* __restrict__ Wk, const float* __restrict__ bk,
    const float* __restrict__ Wv, const float* __restrict__ bv,
    const float* __restrict__ Wco, const float* __restrict__ pos,
    float* __restrict__ outtok){
  __shared__ bf16  feats[SK*CC];       // 44544 B
  __shared__ float qrow[CC];
  __shared__ float qk[CC];             // per-head qk / favh buffer
  __shared__ float offl[SS*2];
  __shared__ float col[KKK*2];
  __shared__ float biasl[SK*NHEADS];
  __shared__ float attnl[NHEADS*SK];
  __shared__ float qb[NHEADS];
  __shared__ int   sidx[SK*4];
  __shared__ float swt[SK*4];

  int blk = blockIdx.x;
  int n = blk % NN, b = blk / NN;
  int iy = n / WW, ix = n % WW;
  int t = threadIdx.x;

  for (int c = t; c < CC; c += 256) qrow[c] = q[(size_t)blk*CC + c];
  for (int i = t; i < SS*2; i += 256) offl[i] = off[(size_t)blk*SS*2 + i];
  __syncthreads();

  // co[kk][g] = tanh(q·Wco_o) * (1/H or 1/W); o = kk*2+g. 18 outputs, 8 lanes each.
  if (t < 144){
    int o = t >> 3, l = t & 7;
    float acc = 0.f;
    for (int c = l; c < CC; c += 8) acc += qrow[c] * Wco[o*CC + c];
    acc += __shfl_xor(acc, 1); acc += __shfl_xor(acc, 2); acc += __shfl_xor(acc, 4);
    if (l == 0){
      int g = o & 1;
      float range = (g == 0) ? (1.0f/HH) : (1.0f/WW);
      col[o] = tanhf(acc) * range;
    }
  }
  // qb[h] = q_h · bk_h   (threads 160..255, 8 lanes per head)
  if (t >= 160){
    int o = t - 160;          // 0..95
    int h = o >> 3, l = o & 7;
    float acc = 0.f;
    for (int d = l; d < HCHAN; d += 8) acc += qrow[h*HCHAN + d] * bk[h*HCHAN + d];
    acc += __shfl_xor(acc, 1); acc += __shfl_xor(acc, 2); acc += __shfl_xor(acc, 4);
    if (l == 0) qb[h] = acc;
  }
  __syncthreads();

  // per-sample bilinear corner indices/weights (grid_sample align_corners=True, zero pad)
  if (t < SK){
    float cy, cx;
    if (t < SS){
      int sy = t / RW, sx = t % RW;
      cy = offl[t*2+0] + ((2.0f*sy)/13.0f*2.0f - 1.0f);
      cx = offl[t*2+1] + ((2.0f*sx)/13.0f*2.0f - 1.0f);
    } else {
      int kk = t - SS;
      float cyr = fminf(fmaxf((float)iy + c_offm[kk][0], 0.f), (float)HH);  // clip to [0,H] (sic)
      float cxr = fminf(fmaxf((float)ix + c_offm[kk][1], 0.f), (float)WW);
      cy = col[kk*2+0] + (cyr/13.0f*2.0f - 1.0f);
      cx = col[kk*2+1] + (cxr/13.0f*2.0f - 1.0f);
    }
    float py = (cy + 1.0f)*0.5f*13.0f;
    float px = (cx + 1.0f)*0.5f*13.0f;
    float y0 = floorf(py), x0 = floorf(px);
    float wy1 = py - y0, wx1 = px - x0;
    #pragma unroll
    for (int k4 = 0; k4 < 4; ++k4){
      float yf = y0 + (k4 >> 1), xf = x0 + (k4 & 1);
      bool valid = (yf >= 0.f) && (yf <= 13.f) && (xf >= 0.f) && (xf <= 13.f);
      int yi = (int)fminf(fmaxf(yf, 0.f), 13.f);
      int xi = (int)fminf(fmaxf(xf, 0.f), 13.f);
      float w = ((k4 >> 1) ? wy1 : (1.f - wy1)) * ((k4 & 1) ? wx1 : (1.f - wx1));
      sidx[t*4 + k4] = ((b*HH + yi)*WW + xi)*CC;
      swt[t*4 + k4] = valid ? w : 0.f;
    }
  }
  __syncthreads();

  // feats[s][c] (bf16, LDS)
  for (int i = t; i < SK*CC; i += 256){
    int s = i / CC, c = i - s*CC;
    const int*   si = sidx + s*4;
    const float* sw = swt  + s*4;
    float v = xh[si[0]+c]*sw[0] + xh[si[1]+c]*sw[1] + xh[si[2]+c]*sw[2] + xh[si[3]+c]*sw[3];
    feats[i] = __float2bfloat16(v);
  }
  // rel-pos bias[s][h] from table (27,27,heads)
  for (int i = t; i < SK*NHEADS; i += 256){
    int s = i / NHEADS, h = i - s*NHEADS;
    float ry, rx;
    if (s < SS){
      int sy = s / RW, sx = s % RW;
      ry = (2.0f*sy - iy)/13.0f - offl[s*2+0];
      rx = (2.0f*sx - ix)/13.0f - offl[s*2+1];
    } else {
      int kk = s - SS;
      ry = col[kk*2+0] - (float)iy;
      rx = col[kk*2+1] - (float)ix;
    }
    float py = (ry + 1.0f)*0.5f*26.0f;
    float px = (rx + 1.0f)*0.5f*26.0f;
    float y0 = floorf(py), x0 = floorf(px);
    float wy1 = py - y0, wx1 = px - x0;
    float val = 0.f;
    #pragma unroll
    for (int k4 = 0; k4 < 4; ++k4){
      float yf = y0 + (k4 >> 1), xf = x0 + (k4 & 1);
      if (yf >= 0.f && yf <= 26.f && xf >= 0.f && xf <= 26.f){
        int yi = (int)yf, xi = (int)xf;
        float w = ((k4 >> 1) ? wy1 : (1.f - wy1)) * ((k4 & 1) ? wx1 : (1.f - wx1));
        val += pos[(h*TH + yi)*TH + xi] * w;
      }
    }
    biasl[s*NHEADS + h] = val;
  }
  __syncthreads();

  // attention logits per head: attn[h][s] = (Wk_h^T q_h)·feat_s + q_h·bk_h + bias
  for (int h = 0; h < NHEADS; ++h){
    for (int c = t; c < CC; c += 256){
      float acc = 0.f;
      const float* wr = Wk + (h*HCHAN)*CC + c;
      #pragma unroll
      for (int d = 0; d < HCHAN; ++d) acc += qrow[h*HCHAN + d] * wr[d*CC];
      qk[c] = acc;
    }
    __syncthreads();
    if (t < SK*4){
      int s = t >> 2, p = t & 3;
      float acc = 0.f;
      for (int c = p; c < CC; c += 4) acc += qk[c] * bf2f(feats[s*CC + c]);
      acc += __shfl_xor(acc, 1); acc += __shfl_xor(acc, 2);
      if (p == 0) attnl[h*SK + s] = acc + qb[h] + biasl[s*NHEADS + h];
    }
    __syncthreads();
  }

  // softmax over s per head
  if (t < NHEADS){
    float mx = -1e30f;
    for (int s = 0; s < SK; ++s) mx = fmaxf(mx, attnl[t*SK + s]);
    float sum = 0.f;
    for (int s = 0; s < SK; ++s){ float e = expf(attnl[t*SK + s] - mx); attnl[t*SK + s] = e; sum += e; }
    float inv = 1.0f/sum;
    for (int s = 0; s < SK; ++s) attnl[t*SK + s] *= inv;
  }
  __syncthreads();

  // out_h = Wv_h · (sum_s attn[h][s] * feat_s) + bv_h   (softmax sums to 1)
  for (int h = 0; h < NHEADS; ++h){
    for (int c = t; c < CC; c += 256){
      float acc = 0.f;
      for (int s = 0; s < SK; ++s) acc += attnl[h*SK + s] * bf2f(feats[s*CC + c]);
      qk[c] = acc;
    }
    __syncthreads();
    {
      int d = t >> 3, l = t & 7;
      float acc = 0.f;
      const float* wr = Wv + (h*HCHAN + d)*CC;
      for (int c = l; c < CC; c += 8) acc += qk[c] * wr[c];
      acc += __shfl_xor(acc, 1); acc += __shfl_xor(acc, 2); acc += __shfl_xor(acc, 4);
      if (l == 0) outtok[(size_t)blk*CC + h*HCHAN + d] = acc + bv[h*HCHAN + d];
    }
    __syncthreads();
  }
}

extern "C" void kernel_launch(void* const* d_in, const int* in_sizes, int n_in,
                              void* d_out, int out_size, void* d_ws, size_t ws_size,
                              hipStream_t stream){
  const float* x    = (const float*)d_in[0];
  const float* Wq   = (const float*)d_in[1];
  const float* bq   = (const float*)d_in[2];
  const float* Wk   = (const float*)d_in[3];
  const float* bk   = (const float*)d_in[4];
  const float* Wv   = (const float*)d_in[5];
  const float* bv   = (const float*)d_in[6];
  const float* Wo1  = (const float*)d_in[7];
  const float* bo1  = (const float*)d_in[8];
  const float* Wdw  = (const float*)d_in[9];
  const float* bdw  = (const float*)d_in[10];
  const float* ln_g = (const float*)d_in[11];
  const float* ln_b = (const float*)d_in[12];
  const float* Wo2  = (const float*)d_in[13];
  const float* Wco  = (const float*)d_in[14];
  const float* pos  = (const float*)d_in[15];
  const float* Wp   = (const float*)d_in[16];
  const float* bp   = (const float*)d_in[17];
  float* out = (float*)d_out;

  float* ws   = (float*)d_ws;
  float* xh   = ws;                 // 602112
  float* qbuf = xh   + 602112;      // 602112
  float* t1   = qbuf + 602112;      // 602112
  float* t2   = t1   + 602112;      // 150528
  float* offp = t2   + 150528;      // 153664
  float* otok = offp + 153664;      // 602112  (total ~10.85 MB f32)

  dim3 gg(49, 12);
  k_transpose<<<2352, 256, 0, stream>>>(x, xh);
  k_gemm<0,0><<<gg, 256, 0, stream>>>(xh,   Wq,  bq,  qbuf, nullptr, 1568);
  k_gemm<1,0><<<gg, 256, 0, stream>>>(qbuf, Wo1, bo1, t1,   nullptr, 1568);
  k_dwln<<<392, 384, 0, stream>>>(t1, Wdw, bdw, ln_g, ln_b, t2);
  k_off<<<392, 256, 0, stream>>>(t2, Wo2, offp);
  k_fused<<<1568, 256, 0, stream>>>(xh, qbuf, offp, Wk, bk, Wv, bv, Wco, pos, otok);
  k_gemm<0,1><<<gg, 256, 0, stream>>>(otok, Wp, bp, nullptr, out, 1568);
}

// Round 4
// 411.767 us; speedup vs baseline: 2.1509x; 2.1509x over previous
//
#include <hip/hip_runtime.h>
#include <hip/hip_bf16.h>
#include <math.h>

#define BB 8
#define CC 384
#define HH 14
#define WW 14
#define NHEADS 12
#define HCHAN 32
#define RH 7
#define RW 7
#define NN 196
#define SS 49
#define KKK 9
#define SK 58
#define TH 27
#define NTOK 1568   // B*N
#define FS 392      // feats LDS row stride (shorts); 392*2=784 B = 49*16 (16B aligned)

typedef float  f4  __attribute__((ext_vector_type(4)));
typedef short  s8  __attribute__((ext_vector_type(8)));
typedef short  s4  __attribute__((ext_vector_type(4)));

__device__ __forceinline__ float geluf(float x){ return 0.5f*x*(1.0f+erff(x*0.7071067811865475f)); }
__device__ __forceinline__ short bf16r(float f){
  unsigned u = __float_as_uint(f);
  u += 0x7fff + ((u>>16)&1u);
  return (short)(u>>16);
}
__device__ __forceinline__ float bs2f(short s){ return __uint_as_float(((unsigned)(unsigned short)s)<<16); }
__device__ __forceinline__ f4 mfma16(s8 a, s8 b, f4 c){
  return __builtin_amdgcn_mfma_f32_16x16x32_bf16(a, b, c, 0, 0, 0);
}

__constant__ float c_offm[9][2] = {{0,-1},{-1,-1},{-1,0},{-1,1},{0,1},{1,1},{1,0},{1,-1},{0,0}};

// ---------------- transpose B,C,H,W (f32) -> B,H,W,C (f32) ----------------
__global__ void k_transpose(const float* __restrict__ x, float* __restrict__ xh){
  int i = blockIdx.x*256 + threadIdx.x;
  if (i >= BB*HH*WW*CC) return;
  int c = i % CC; int p = i / CC;
  int xx = p % WW; p /= WW;
  int y = p % HH; int b = p / HH;
  xh[i] = x[((b*CC + c)*HH + y)*WW + xx];
}

// ---------------- f32 tiled GEMM (R2-proven): C[m,o] = act(A[m,:]·Wt[o,:] + bias[o]) ----
template<int ACT, int OUTMODE>
__global__ void __launch_bounds__(256) k_gemm(const float* __restrict__ A,
                       const float* __restrict__ Wt, const float* __restrict__ bias,
                       float* __restrict__ Co, float* __restrict__ Cb, int M){
  __shared__ float As[32][33];
  __shared__ float Ws[32][33];
  int m0 = blockIdx.x*32, o0 = blockIdx.y*32;
  int tx = threadIdx.x & 15, ty = threadIdx.x >> 4;
  float acc00=0.f, acc01=0.f, acc10=0.f, acc11=0.f;
  for (int k0 = 0; k0 < CC; k0 += 32){
    for (int l = threadIdx.x; l < 1024; l += 256){
      int r = l >> 5, cc = l & 31;
      int m = m0 + r;
      As[r][cc] = (m < M) ? A[m*CC + k0 + cc] : 0.f;
      Ws[r][cc] = Wt[(o0 + r)*CC + k0 + cc];
    }
    __syncthreads();
    #pragma unroll
    for (int kk = 0; kk < 32; ++kk){
      float a0 = As[ty*2][kk],   a1 = As[ty*2+1][kk];
      float w0 = Ws[tx*2][kk],   w1 = Ws[tx*2+1][kk];
      acc00 += a0*w0; acc01 += a0*w1; acc10 += a1*w0; acc11 += a1*w1;
    }
    __syncthreads();
  }
  float accs[2][2] = {{acc00,acc01},{acc10,acc11}};
  #pragma unroll
  for (int i = 0; i < 2; ++i)
  #pragma unroll
  for (int j = 0; j < 2; ++j){
    int m = m0 + ty*2 + i, o = o0 + tx*2 + j;
    if (m >= M) continue;
    float v = accs[i][j] + bias[o];
    if (ACT == 1) v = geluf(v);
    if (OUTMODE == 0) Co[m*CC + o] = v;
    else {
      int b = m / NN, n = m % NN;
      Cb[(b*CC + o)*NN + n] = v;
    }
  }
}

// ---------------- depthwise 3x3 s2 conv + LN + GELU (f32) -----------------
__global__ void __launch_bounds__(384) k_dwln(const float* __restrict__ t1,
      const float* __restrict__ Wdw, const float* __restrict__ bdw,
      const float* __restrict__ lng, const float* __restrict__ lnb,
      float* __restrict__ t2){
  int blk = blockIdx.x;
  int ow = blk % RW; int oh = (blk / RW) % RH; int b = blk / (RH*RW);
  int c = threadIdx.x;
  float acc = bdw[c];
  #pragma unroll
  for (int kh = 0; kh < 3; ++kh){
    int ih = oh*2 - 1 + kh;
    if (ih < 0 || ih >= HH) continue;
    #pragma unroll
    for (int kw = 0; kw < 3; ++kw){
      int iw = ow*2 - 1 + kw;
      if (iw < 0 || iw >= WW) continue;
      acc += t1[((b*HH + ih)*WW + iw)*CC + c] * Wdw[c*9 + kh*3 + kw];
    }
  }
  __shared__ float red[6];
  __shared__ float s_mu, s_rv;
  float v = acc;
  #pragma unroll
  for (int o = 32; o > 0; o >>= 1) v += __shfl_down(v, o);
  int wid = c >> 6, lane = c & 63;
  if (lane == 0) red[wid] = v;
  __syncthreads();
  if (c == 0){ float s = 0.f; for (int i = 0; i < 6; ++i) s += red[i]; s_mu = s / CC; }
  __syncthreads();
  float mu = s_mu;
  float d = acc - mu;
  v = d*d;
  #pragma unroll
  for (int o = 32; o > 0; o >>= 1) v += __shfl_down(v, o);
  if (lane == 0) red[wid] = v;
  __syncthreads();
  if (c == 0){ float s = 0.f; for (int i = 0; i < 6; ++i) s += red[i]; s_rv = rsqrtf(s / CC + 1e-5f); }
  __syncthreads();
  float val = d * s_rv * lng[c] + lnb[c];
  t2[blk*CC + c] = geluf(val);
}

// ---------------- offset head (f32, f4-vectorized): off = tanh(t2·Wo2)*range*2 ----
__global__ void __launch_bounds__(256) k_off(const float* __restrict__ t2,
      const float* __restrict__ Wo2, float* __restrict__ off){
  int blk = blockIdx.x;                // b*SS + s
  int s = blk % SS; int b = blk / SS;
  __shared__ float row[CC];
  for (int c = threadIdx.x; c < CC; c += 256) row[c] = t2[blk*CC + c];
  __syncthreads();
  for (int j = threadIdx.x; j < 2*NN; j += 256){
    const float* wr = Wo2 + j*CC;
    f4 a4 = {0.f,0.f,0.f,0.f};
    for (int c = 0; c < CC; c += 4){
      f4 w = *(const f4*)(wr + c);
      f4 r = *(const f4*)(row + c);
      a4 += r * w;
    }
    float acc = a4[0]+a4[1]+a4[2]+a4[3];
    int g = j / NN, n = j % NN;
    float range = (g == 0) ? (1.0f/HH) : (1.0f/WW);
    off[((b*NN + n)*SS + s)*2 + g] = tanhf(acc) * range * 2.0f;
  }
}

// ---------------- qk'[tok][h*384+c] = sum_d q[tok][h*32+d]*Wk[h*32+d][c], f32 -> bf16 hi/lo ----
__global__ void __launch_bounds__(256) k_qkp(const float* __restrict__ q, const float* __restrict__ Wk,
                                             short* __restrict__ qkh, short* __restrict__ qkl_){
  __shared__ float ql[8*384];
  int tb = blockIdx.x*8;
  int t = threadIdx.x;
  for (int i = t; i < 768; i += 256){
    int tk = i / 96, c4 = (i - tk*96)*4;
    *(f4*)(ql + tk*384 + c4) = *(const f4*)(q + (size_t)(tb + tk)*384 + c4);
  }
  __syncthreads();
  for (int oc = t; oc < 1152; oc += 256){
    int h = oc / 96; int c4 = (oc - h*96)*4;
    f4 acc[8];
    #pragma unroll
    for (int tk = 0; tk < 8; ++tk) acc[tk] = (f4){0.f,0.f,0.f,0.f};
    const float* wbase = Wk + (size_t)h*32*384 + c4;
    for (int d = 0; d < 32; ++d){
      f4 wv = *(const f4*)(wbase + (size_t)d*384);
      #pragma unroll
      for (int tk = 0; tk < 8; ++tk){
        float qv = ql[tk*384 + h*32 + d];
        acc[tk] += qv * wv;
      }
    }
    #pragma unroll
    for (int tk = 0; tk < 8; ++tk){
      #pragma unroll
      for (int j = 0; j < 4; ++j){
        float v = acc[tk][j];
        short hi = bf16r(v);
        short lo = bf16r(v - bs2f(hi));
        size_t o = (size_t)(tb + tk)*4608 + h*384 + c4 + j;
        qkh[o] = hi; qkl_[o] = lo;
      }
    }
  }
}

// ---------------- fused per-token attention: MFMA logits + weighted-V (hi/lo precise) ----
__global__ void __launch_bounds__(256) k_fused(
    const float* __restrict__ xh, const float* __restrict__ qf, const float* __restrict__ off,
    const short* __restrict__ qkh, const short* __restrict__ qkl_,
    const float* __restrict__ bk, const float* __restrict__ Wco, const float* __restrict__ pos,
    short* __restrict__ favh, short* __restrict__ favl){
  __shared__ short feats[64*FS];    // 50176 B; rows 58..63 zeroed (P4 k-dim)
  __shared__ short attnbh[16*72];   // 2304 B
  __shared__ short attnbl[16*72];   // 2304 B
  __shared__ float scoreS[16*66];   // 4224 B: bias (P1b) -> logits (P2) -> probs src (P3)
  __shared__ float qrow[384];
  __shared__ float offl[98];
  __shared__ float colb[18];
  __shared__ float qb[16];
  __shared__ int   sidx[58*4];
  __shared__ float swt[58*4];

  int blk = blockIdx.x;
  int n = blk % NN, b = blk / NN;
  int iy = n / WW, ix = n % WW;
  int t = threadIdx.x;

  // ---- P0 ----
  for (int c = t; c < 384; c += 256) qrow[c] = qf[(size_t)blk*384 + c];
  for (int i = t; i < 98; i += 256) offl[i] = off[(size_t)blk*98 + i];
  for (int i = t; i < 6*FS; i += 256) feats[58*FS + i] = 0;
  for (int i = t; i < 1152; i += 256){ attnbh[i] = 0; attnbl[i] = 0; }
  if (t < 4) qb[12 + t] = 0.f;
  __syncthreads();

  // ---- P1a: colb (co) and qb[h]=q_h·bk_h ----
  if (t < 144){
    int o = t >> 3, l = t & 7;
    float acc = 0.f;
    for (int c = l; c < 384; c += 8) acc += qrow[c] * Wco[o*384 + c];
    acc += __shfl_xor(acc, 1); acc += __shfl_xor(acc, 2); acc += __shfl_xor(acc, 4);
    if (l == 0){
      int g = o & 1;
      float range = (g == 0) ? (1.0f/HH) : (1.0f/WW);
      colb[o] = tanhf(acc) * range;
    }
  }
  if (t >= 160){
    int o = t - 160;
    int h = o >> 3, l = o & 7;
    float acc = 0.f;
    for (int d = l; d < 32; d += 8) acc += qrow[h*32 + d] * bk[h*32 + d];
    acc += __shfl_xor(acc, 1); acc += __shfl_xor(acc, 2); acc += __shfl_xor(acc, 4);
    if (l == 0 && h < 12) qb[h] = acc;
  }
  __syncthreads();

  // ---- P1b: bilinear corners + rel-pos bias into scoreS ----
  if (t < SK){
    float cy, cx;
    if (t < SS){
      int sy = t / RW, sx = t % RW;
      cy = offl[t*2+0] + ((2.0f*sy)/13.0f*2.0f - 1.0f);
      cx = offl[t*2+1] + ((2.0f*sx)/13.0f*2.0f - 1.0f);
    } else {
      int kk = t - SS;
      float cyr = fminf(fmaxf((float)iy + c_offm[kk][0], 0.f), (float)HH);
      float cxr = fminf(fmaxf((float)ix + c_offm[kk][1], 0.f), (float)WW);
      cy = colb[kk*2+0] + (cyr/13.0f*2.0f - 1.0f);
      cx = colb[kk*2+1] + (cxr/13.0f*2.0f - 1.0f);
    }
    float py = (cy + 1.0f)*0.5f*13.0f;
    float px = (cx + 1.0f)*0.5f*13.0f;
    float y0 = floorf(py), x0 = floorf(px);
    float wy1 = py - y0, wx1 = px - x0;
    #pragma unroll
    for (int k4 = 0; k4 < 4; ++k4){
      float yf = y0 + (k4 >> 1), xf = x0 + (k4 & 1);
      bool valid = (yf >= 0.f) && (yf <= 13.f) && (xf >= 0.f) && (xf <= 13.f);
      int yi = (int)fminf(fmaxf(yf, 0.f), 13.f);
      int xi = (int)fminf(fmaxf(xf, 0.f), 13.f);
      float wgt = ((k4 >> 1) ? wy1 : (1.f - wy1)) * ((k4 & 1) ? wx1 : (1.f - wx1));
      sidx[t*4 + k4] = ((b*HH + yi)*WW + xi)*CC;
      swt[t*4 + k4] = valid ? wgt : 0.f;
    }
  }
  for (int i = t; i < SK*NHEADS; i += 256){
    int s = i / NHEADS, h = i - s*NHEADS;
    float ry, rx;
    if (s < SS){
      int sy = s / RW, sx = s % RW;
      ry = (2.0f*sy - iy)/13.0f - offl[s*2+0];
      rx = (2.0f*sx - ix)/13.0f - offl[s*2+1];
    } else {
      int kk = s - SS;
      ry = colb[kk*2+0] - (float)iy;
      rx = colb[kk*2+1] - (float)ix;
    }
    float py = (ry + 1.0f)*0.5f*26.0f;
    float px = (rx + 1.0f)*0.5f*26.0f;
    float y0 = floorf(py), x0 = floorf(px);
    float wy1 = py - y0, wx1 = px - x0;
    float val = 0.f;
    #pragma unroll
    for (int k4 = 0; k4 < 4; ++k4){
      float yf = y0 + (k4 >> 1), xf = x0 + (k4 & 1);
      if (yf >= 0.f && yf <= 26.f && xf >= 0.f && xf <= 26.f){
        int yi = (int)yf, xi = (int)xf;
        float wgt = ((k4 >> 1) ? wy1 : (1.f - wy1)) * ((k4 & 1) ? wx1 : (1.f - wx1));
        val += pos[(h*TH + yi)*TH + xi] * wgt;
      }
    }
    scoreS[h*66 + s] = val;
  }
  __syncthreads();

  // ---- P1c: bilinear gather -> feats (bf16 single; R2-proven precision) ----
  for (int i = t; i < 58*96; i += 256){
    int s = i / 96, c4 = (i - s*96)*4;
    const int*   si = sidx + s*4;
    const float* sw = swt  + s*4;
    f4 v0 = *(const f4*)(xh + si[0] + c4);
    f4 v1 = *(const f4*)(xh + si[1] + c4);
    f4 v2 = *(const f4*)(xh + si[2] + c4);
    f4 v3 = *(const f4*)(xh + si[3] + c4);
    s4 o;
    #pragma unroll
    for (int j = 0; j < 4; ++j)
      o[j] = bf16r(v0[j]*sw[0] + v1[j]*sw[1] + v2[j]*sw[2] + v3[j]*sw[3]);
    *(s4*)(feats + s*FS + c4) = o;
  }
  __syncthreads();

  // ---- P2: logits D[h][s] = qk'_hi·feats + qk'_lo·feats, C-init = bias + qb ----
  {
    int w = t>>6, lane = t&63, col = lane&15, quad = lane>>4;
    const short* qh = qkh  + (size_t)blk*4608 + col*384;
    const short* ql = qkl_ + (size_t)blk*4608 + col*384;
    f4 acc;
    #pragma unroll
    for (int r = 0; r < 4; ++r){
      int h = quad*4 + r;
      acc[r] = scoreS[h*66 + w*16 + col] + qb[h];
    }
    for (int k0 = 0; k0 < 384; k0 += 32){
      s8 ah = *(const s8*)(qh + k0 + quad*8);
      s8 al = *(const s8*)(ql + k0 + quad*8);
      s8 bfr = *(const s8*)(feats + (w*16 + col)*FS + k0 + quad*8);
      acc = mfma16(ah, bfr, acc);
      acc = mfma16(al, bfr, acc);
    }
    #pragma unroll
    for (int r = 0; r < 4; ++r)
      scoreS[(quad*4 + r)*66 + w*16 + col] = acc[r];
  }
  __syncthreads();

  // ---- P3: softmax per head -> attn probs as bf16 hi/lo ----
  if (t < 192){
    int h = t >> 4, l = t & 15;
    float v[4];
    #pragma unroll
    for (int k = 0; k < 4; ++k){ int s = l + 16*k; v[k] = (s < SK) ? scoreS[h*66 + s] : -1e30f; }
    float mx = fmaxf(fmaxf(v[0], v[1]), fmaxf(v[2], v[3]));
    mx = fmaxf(mx, __shfl_xor(mx, 1)); mx = fmaxf(mx, __shfl_xor(mx, 2));
    mx = fmaxf(mx, __shfl_xor(mx, 4)); mx = fmaxf(mx, __shfl_xor(mx, 8));
    float e[4], sum = 0.f;
    #pragma unroll
    for (int k = 0; k < 4; ++k){ int s = l + 16*k; e[k] = (s < SK) ? expf(v[k] - mx) : 0.f; sum += e[k]; }
    sum += __shfl_xor(sum, 1); sum += __shfl_xor(sum, 2);
    sum += __shfl_xor(sum, 4); sum += __shfl_xor(sum, 8);
    float inv = 1.0f / sum;
    #pragma unroll
    for (int k = 0; k < 4; ++k){
      int s = l + 16*k;
      if (s < SK){
        float p = e[k]*inv;
        short hi = bf16r(p);
        attnbh[h*72 + s] = hi;
        attnbl[h*72 + s] = bf16r(p - bs2f(hi));
      }
    }
  }
  __syncthreads();

  // ---- P4: fav[h][c] = sum_s attn[h][s]*feats[s][c] (hi/lo), write bf16 hi/lo ----
  {
    int w = t>>6, lane = t&63, col = lane&15, quad = lane>>4;
    s8 a0h = *(const s8*)(attnbh + col*72 + quad*8);
    s8 a0l = *(const s8*)(attnbl + col*72 + quad*8);
    s8 a1h = *(const s8*)(attnbh + col*72 + 32 + quad*8);
    s8 a1l = *(const s8*)(attnbl + col*72 + 32 + quad*8);
    for (int i = 0; i < 6; ++i){
      int c = (w*6 + i)*16 + col;
      s8 b0, b1;
      #pragma unroll
      for (int j = 0; j < 8; ++j){
        b0[j] = feats[(quad*8 + j)*FS + c];
        b1[j] = feats[(32 + quad*8 + j)*FS + c];
      }
      f4 acc = {0.f,0.f,0.f,0.f};
      acc = mfma16(a0h, b0, acc);
      acc = mfma16(a0l, b0, acc);
      acc = mfma16(a1h, b1, acc);
      acc = mfma16(a1l, b1, acc);
      #pragma unroll
      for (int r = 0; r < 4; ++r){
        int h = quad*4 + r;
        if (h < 12){
          float v = acc[r];
          short hi = bf16r(v);
          favh[(size_t)blk*4608 + h*384 + c] = hi;
          favl[(size_t)blk*4608 + h*384 + c] = bf16r(v - bs2f(hi));
        }
      }
    }
  }
}

// ---------------- per-head Wv projection: otok[m][h*32+o] = fav_h[m]·Wv_h[o] + bv ----
__global__ void __launch_bounds__(256) k_wv(const short* __restrict__ favh, const short* __restrict__ favl,
                                            const float* __restrict__ Wv, const float* __restrict__ bv,
                                            float* __restrict__ otok){
  __shared__ float As[32][33];
  __shared__ float Ws[32][33];
  int m0 = blockIdx.x*32; int h = blockIdx.y;
  int tx = threadIdx.x & 15, ty = threadIdx.x >> 4;
  float acc00=0.f, acc01=0.f, acc10=0.f, acc11=0.f;
  for (int k0 = 0; k0 < 384; k0 += 32){
    for (int l = threadIdx.x; l < 1024; l += 256){
      int r = l >> 5, cc = l & 31;
      size_t fo = (size_t)(m0 + r)*4608 + h*384 + k0 + cc;
      As[r][cc] = bs2f(favh[fo]) + bs2f(favl[fo]);
      Ws[r][cc] = Wv[(size_t)(h*32 + r)*384 + k0 + cc];
    }
    __syncthreads();
    #pragma unroll
    for (int kk = 0; kk < 32; ++kk){
      float a0 = As[ty*2][kk],   a1 = As[ty*2+1][kk];
      float w0 = Ws[tx*2][kk],   w1 = Ws[tx*2+1][kk];
      acc00 += a0*w0; acc01 += a0*w1; acc10 += a1*w0; acc11 += a1*w1;
    }
    __syncthreads();
  }
  float accs[2][2] = {{acc00,acc01},{acc10,acc11}};
  #pragma unroll
  for (int i = 0; i < 2; ++i)
  #pragma unroll
  for (int j = 0; j < 2; ++j){
    int m = m0 + ty*2 + i;
    int o = h*32 + tx*2 + j;
    otok[(size_t)m*384 + o] = accs[i][j] + bv[o];
  }
}

extern "C" void kernel_launch(void* const* d_in, const int* in_sizes, int n_in,
                              void* d_out, int out_size, void* d_ws, size_t ws_size,
                              hipStream_t stream){
  const float* x    = (const float*)d_in[0];
  const float* Wq   = (const float*)d_in[1];
  const float* bq   = (const float*)d_in[2];
  const float* Wk   = (const float*)d_in[3];
  const float* bk   = (const float*)d_in[4];
  const float* Wv   = (const float*)d_in[5];
  const float* bv   = (const float*)d_in[6];
  const float* Wo1  = (const float*)d_in[7];
  const float* bo1  = (const float*)d_in[8];
  const float* Wdw  = (const float*)d_in[9];
  const float* bdw  = (const float*)d_in[10];
  const float* ln_g = (const float*)d_in[11];
  const float* ln_b = (const float*)d_in[12];
  const float* Wo2  = (const float*)d_in[13];
  const float* Wco  = (const float*)d_in[14];
  const float* pos  = (const float*)d_in[15];
  const float* Wp   = (const float*)d_in[16];
  const float* bp   = (const float*)d_in[17];
  float* out = (float*)d_out;

  float* ws   = (float*)d_ws;
  float* xh   = ws;                  // 602112 f32
  float* qf   = xh   + 602112;       // 602112 f32
  float* t1   = qf   + 602112;       // 602112 f32
  float* t2   = t1   + 602112;       // 150528 f32
  float* offp = t2   + 150528;       // 153664 f32
  float* otok = offp + 153664;       // 602112 f32
  short* qkh  = (short*)(otok + 602112);   // 1568*4608 + 2048 pad (overread guard)
  short* qkl_ = qkh + (7225344 + 2048);    // same size
  // fav hi/lo alias qk hi/lo: per-token region consumed (P2) before written (P4)
  short* favh = qkh;
  short* favl = qkl_;
  // total ws ~= 10.85 MB f32 + 28.9 MB bf16 ~= 39.8 MB

  dim3 gg(49, 12);
  k_transpose<<<2352, 256, 0, stream>>>(x, xh);
  k_gemm<0,0><<<gg, 256, 0, stream>>>(xh, Wq,  bq,  qf, nullptr, NTOK);
  k_gemm<1,0><<<gg, 256, 0, stream>>>(qf, Wo1, bo1, t1, nullptr, NTOK);
  k_dwln<<<392, 384, 0, stream>>>(t1, Wdw, bdw, ln_g, ln_b, t2);
  k_off<<<392, 256, 0, stream>>>(t2, Wo2, offp);
  k_qkp<<<196, 256, 0, stream>>>(qf, Wk, qkh, qkl_);
  k_fused<<<1568, 256, 0, stream>>>(xh, qf, offp, qkh, qkl_, bk, Wco, pos, favh, favl);
  k_wv<<<gg, 256, 0, stream>>>(favh, favl, Wv, bv, otok);
  k_gemm<0,1><<<gg, 256, 0, stream>>>(otok, Wp, bp, nullptr, out, NTOK);
}

// Round 5
// 286.967 us; speedup vs baseline: 3.0863x; 1.4349x over previous
//
#include <hip/hip_runtime.h>
#include <hip/hip_bf16.h>
#include <math.h>

#define BB 8
#define CC 384
#define HH 14
#define WW 14
#define NHEADS 12
#define RH 7
#define RW 7
#define NN 196
#define SS 49
#define KKK 9
#define SK 58
#define TH 27
#define NTOK 1568

typedef float f4 __attribute__((ext_vector_type(4)));
typedef int   i4 __attribute__((ext_vector_type(4)));
typedef short s8 __attribute__((ext_vector_type(8)));
typedef short s4 __attribute__((ext_vector_type(4)));

__device__ __forceinline__ float geluf(float x){ return 0.5f*x*(1.0f+erff(x*0.7071067811865475f)); }
__device__ __forceinline__ short bf16r(float f){
  unsigned u = __float_as_uint(f);
  u += 0x7fff + ((u>>16)&1u);
  return (short)(u>>16);
}
__device__ __forceinline__ float bs2f(short s){ return __uint_as_float(((unsigned)(unsigned short)s)<<16); }
__device__ __forceinline__ int packhl(float v){
  short hi = bf16r(v);
  short lo = bf16r(v - bs2f(hi));
  return (int)((unsigned short)hi | ((unsigned)(unsigned short)lo << 16));
}
__device__ __forceinline__ f4 mfma16(s8 a, s8 b, f4 c){
  return __builtin_amdgcn_mfma_f32_16x16x32_bf16(a, b, c, 0, 0, 0);
}

__constant__ float c_offm[9][2] = {{0,-1},{-1,-1},{-1,0},{-1,1},{0,1},{1,1},{1,0},{1,-1},{0,0}};

// ---------------- transpose B,C,H,W (f32) -> B,H,W,C (f32) ----------------
__global__ void k_transpose(const float* __restrict__ x, float* __restrict__ xh){
  int i = blockIdx.x*256 + threadIdx.x;
  if (i >= BB*HH*WW*CC) return;
  int c = i % CC; int p = i / CC;
  int xx = p % WW; p /= WW;
  int y = p % HH; int b = p / HH;
  xh[i] = x[((b*CC + c)*HH + y)*WW + xx];
}

// ---------------- staged bf16 hi/lo MFMA GEMM, f32 in/out -------------------
// D[m][o] = epi(A[m,:]·W[o,:] + bias[o]); K=384. Tile 64m x 64n.
// EPI: 0 plain, 1 gelu, 2 scatter out[(b*384+o)*196+n], 3 tanh-offset scatter
template<int EPI>
__global__ void __launch_bounds__(256) k_mmf(const float* __restrict__ A, const float* __restrict__ W,
                                             const float* __restrict__ bias, float* __restrict__ out,
                                             int M, int N){
  __shared__ short Ah[64][40], Al[64][40], Bh[64][40], Bl[64][40];
  int t = threadIdx.x;
  int w = t>>6, lane = t&63, col = lane&15, quad = lane>>4;
  int m0 = blockIdx.x*64, n0 = blockIdx.y*64;
  int r = t>>2, cg = t&3;
  int arow = min(m0 + r, M-1);
  int brow = min(n0 + r, N-1);
  f4 acc[4] = {{0,0,0,0},{0,0,0,0},{0,0,0,0},{0,0,0,0}};
  for (int k0 = 0; k0 < 384; k0 += 32){
    f4 a0 = *(const f4*)(A + (size_t)arow*384 + k0 + cg*8);
    f4 a1 = *(const f4*)(A + (size_t)arow*384 + k0 + cg*8 + 4);
    f4 b0 = *(const f4*)(W + (size_t)brow*384 + k0 + cg*8);
    f4 b1 = *(const f4*)(W + (size_t)brow*384 + k0 + cg*8 + 4);
    s8 ah, al, bh, bl;
    #pragma unroll
    for (int j = 0; j < 4; ++j){
      ah[j] = bf16r(a0[j]); al[j] = bf16r(a0[j] - bs2f(ah[j]));
      ah[4+j] = bf16r(a1[j]); al[4+j] = bf16r(a1[j] - bs2f(ah[4+j]));
      bh[j] = bf16r(b0[j]); bl[j] = bf16r(b0[j] - bs2f(bh[j]));
      bh[4+j] = bf16r(b1[j]); bl[4+j] = bf16r(b1[j] - bs2f(bh[4+j]));
    }
    __syncthreads();
    *(s8*)&Ah[r][cg*8] = ah; *(s8*)&Al[r][cg*8] = al;
    *(s8*)&Bh[r][cg*8] = bh; *(s8*)&Bl[r][cg*8] = bl;
    __syncthreads();
    s8 afh = *(const s8*)&Ah[w*16+col][quad*8];
    s8 afl = *(const s8*)&Al[w*16+col][quad*8];
    #pragma unroll
    for (int nt = 0; nt < 4; ++nt){
      s8 bfh = *(const s8*)&Bh[nt*16+col][quad*8];
      s8 bfl = *(const s8*)&Bl[nt*16+col][quad*8];
      acc[nt] = mfma16(afh, bfh, acc[nt]);
      acc[nt] = mfma16(afl, bfh, acc[nt]);
      acc[nt] = mfma16(afh, bfl, acc[nt]);
    }
  }
  #pragma unroll
  for (int nt = 0; nt < 4; ++nt){
    #pragma unroll
    for (int rr = 0; rr < 4; ++rr){
      int m = m0 + w*16 + quad*4 + rr;
      int o = n0 + nt*16 + col;
      if (m >= M || o >= N) continue;
      float v = acc[nt][rr];
      if (EPI == 0){ out[(size_t)m*384 + o] = v + bias[o]; }
      else if (EPI == 1){ out[(size_t)m*384 + o] = geluf(v + bias[o]); }
      else if (EPI == 2){
        int b = m / NN, n = m % NN;
        out[((size_t)b*384 + o)*NN + n] = v + bias[o];
      } else {
        int g = o / NN, nn = o % NN;
        int b = m / SS, s = m % SS;
        float rng = (g == 0) ? (1.0f/HH) : (1.0f/WW);
        out[((b*NN + nn)*SS + s)*2 + g] = tanhf(v) * rng * 2.0f;
      }
    }
  }
}

// ---------------- depthwise 3x3 s2 conv + LN + GELU (f32) -----------------
__global__ void __launch_bounds__(384) k_dwln(const float* __restrict__ t1,
      const float* __restrict__ Wdw, const float* __restrict__ bdw,
      const float* __restrict__ lng, const float* __restrict__ lnb,
      float* __restrict__ t2){
  int blk = blockIdx.x;
  int ow = blk % RW; int oh = (blk / RW) % RH; int b = blk / (RH*RW);
  int c = threadIdx.x;
  float acc = bdw[c];
  #pragma unroll
  for (int kh = 0; kh < 3; ++kh){
    int ih = oh*2 - 1 + kh;
    if (ih < 0 || ih >= HH) continue;
    #pragma unroll
    for (int kw = 0; kw < 3; ++kw){
      int iw = ow*2 - 1 + kw;
      if (iw < 0 || iw >= WW) continue;
      acc += t1[((b*HH + ih)*WW + iw)*CC + c] * Wdw[c*9 + kh*3 + kw];
    }
  }
  __shared__ float red[6];
  __shared__ float s_mu, s_rv;
  float v = acc;
  #pragma unroll
  for (int o = 32; o > 0; o >>= 1) v += __shfl_down(v, o);
  int wid = c >> 6, lane = c & 63;
  if (lane == 0) red[wid] = v;
  __syncthreads();
  if (c == 0){ float s = 0.f; for (int i = 0; i < 6; ++i) s += red[i]; s_mu = s / CC; }
  __syncthreads();
  float mu = s_mu;
  float d = acc - mu;
  v = d*d;
  #pragma unroll
  for (int o = 32; o > 0; o >>= 1) v += __shfl_down(v, o);
  if (lane == 0) red[wid] = v;
  __syncthreads();
  if (c == 0){ float s = 0.f; for (int i = 0; i < 6; ++i) s += red[i]; s_rv = rsqrtf(s / CC + 1e-5f); }
  __syncthreads();
  float val = d * s_rv * lng[c] + lnb[c];
  t2[blk*CC + c] = geluf(val);
}

// ---------------- qk'[tok][h*384+c] packed hi|lo int ------------------------
__global__ void __launch_bounds__(256) k_qkp(const float* __restrict__ q, const float* __restrict__ Wk,
                                             int* __restrict__ qkhl){
  __shared__ float ql[8*384];
  int tb = blockIdx.x*8;
  int t = threadIdx.x;
  for (int i = t; i < 768; i += 256){
    int tk = i / 96, c4 = (i - tk*96)*4;
    *(f4*)(ql + tk*384 + c4) = *(const f4*)(q + (size_t)(tb + tk)*384 + c4);
  }
  __syncthreads();
  for (int oc = t; oc < 1152; oc += 256){
    int h = oc / 96; int c4 = (oc - h*96)*4;
    f4 acc[8];
    #pragma unroll
    for (int tk = 0; tk < 8; ++tk) acc[tk] = (f4){0.f,0.f,0.f,0.f};
    const float* wbase = Wk + (size_t)h*32*384 + c4;
    for (int d = 0; d < 32; ++d){
      f4 wv = *(const f4*)(wbase + (size_t)d*384);
      #pragma unroll
      for (int tk = 0; tk < 8; ++tk) acc[tk] += ql[tk*384 + h*32 + d] * wv;
    }
    #pragma unroll
    for (int tk = 0; tk < 8; ++tk){
      i4 pv;
      #pragma unroll
      for (int j = 0; j < 4; ++j) pv[j] = packhl(acc[tk][j]);
      *(i4*)(qkhl + (size_t)(tb + tk)*4608 + h*384 + c4) = pv;
    }
  }
}

// ---------------- fused per-token attention --------------------------------
// LDS layout (shorts): feats[58*392] | attnbh[16*72] | attnbl[16*72] | zpad[48]
//   (attnb+zpad region = exactly feats rows 58..63 for P4's k-pad: bf16-safe)
// uni (f32[768], 3072B): scoreS[12*64] aliases {qrow[384] | swf[232] | sidx16[232 u16]}
__global__ void __launch_bounds__(256, 3) k_fused(
    const float* __restrict__ xh, const float* __restrict__ qf, const float* __restrict__ off,
    const int* __restrict__ qkhl,
    const float* __restrict__ bk, const float* __restrict__ Wco, const float* __restrict__ pos,
    int* __restrict__ favhl){
  __shared__ short smem[25088];
  __shared__ float uni[768];
  __shared__ float offl[98];
  __shared__ float colb[18];
  __shared__ float qbv[12];

  short* feats  = smem;
  short* attnbh = smem + 22736;
  short* attnbl = smem + 23888;
  float* qrow   = uni;
  float* scoreS = uni;            // [12][64], clobbers qrow/swf/sidx16 at P2
  float* swf    = uni + 384;      // [58*4]
  unsigned short* sidx16 = (unsigned short*)(uni + 616); // [58*4]

  int blk = blockIdx.x;
  int n = blk % NN, b = blk / NN;
  int iy = n / WW, ix = n % WW;
  int t = threadIdx.x;
  int w = t>>6, lane = t&63, colh = lane&15, quad = lane>>4;

  // ---- qk prefetch (HBM latency overlapped with P0/P1a) ----
  const int* qbase = qkhl + (size_t)blk*4608 + colh*384 + quad*8;
  i4 pf[12];
  #pragma unroll
  for (int kt = 0; kt < 6; ++kt){
    pf[2*kt]   = *(const i4*)(qbase + kt*32);
    pf[2*kt+1] = *(const i4*)(qbase + kt*32 + 4);
  }

  // ---- P0 ----
  for (int c = t; c < 384; c += 256) qrow[c] = qf[(size_t)blk*384 + c];
  for (int i = t; i < 98; i += 256) offl[i] = off[(size_t)blk*98 + i];
  for (int i = t; i < 2352; i += 256) smem[22736 + i] = 0;   // attnb + zpad
  __syncthreads();

  // ---- P1a: colb (co) and qbv[h]=q_h·bk_h ----
  if (t < 144){
    int o = t >> 3, l = t & 7;
    const float* wr = Wco + o*384 + l*48;
    const float* qr = qrow + l*48;
    f4 a4 = {0.f,0.f,0.f,0.f};
    #pragma unroll
    for (int c = 0; c < 48; c += 4) a4 += (*(const f4*)(qr + c)) * (*(const f4*)(wr + c));
    float acc = a4[0]+a4[1]+a4[2]+a4[3];
    acc += __shfl_xor(acc, 1); acc += __shfl_xor(acc, 2); acc += __shfl_xor(acc, 4);
    if (l == 0){
      int g = o & 1;
      float range = (g == 0) ? (1.0f/HH) : (1.0f/WW);
      colb[o] = tanhf(acc) * range;
    }
  }
  if (t >= 160){
    int o = t - 160;
    int h = o >> 3, l = o & 7;
    float acc = 0.f;
    for (int d = l; d < 32; d += 8) acc += qrow[h*32 + d] * bk[h*32 + d];
    acc += __shfl_xor(acc, 1); acc += __shfl_xor(acc, 2); acc += __shfl_xor(acc, 4);
    if (l == 0 && h < 12) qbv[h] = acc;
  }
  __syncthreads();

  // ---- P1-prep: bilinear corner idx/weights ----
  if (t < SK){
    float cy, cx;
    if (t < SS){
      int sy = t / RW, sx = t % RW;
      cy = offl[t*2+0] + ((2.0f*sy)/13.0f*2.0f - 1.0f);
      cx = offl[t*2+1] + ((2.0f*sx)/13.0f*2.0f - 1.0f);
    } else {
      int kk = t - SS;
      float cyr = fminf(fmaxf((float)iy + c_offm[kk][0], 0.f), (float)HH);
      float cxr = fminf(fmaxf((float)ix + c_offm[kk][1], 0.f), (float)WW);
      cy = colb[kk*2+0] + (cyr/13.0f*2.0f - 1.0f);
      cx = colb[kk*2+1] + (cxr/13.0f*2.0f - 1.0f);
    }
    float py = (cy + 1.0f)*0.5f*13.0f;
    float px = (cx + 1.0f)*0.5f*13.0f;
    float y0 = floorf(py), x0 = floorf(px);
    float wy1 = py - y0, wx1 = px - x0;
    #pragma unroll
    for (int k4 = 0; k4 < 4; ++k4){
      float yf = y0 + (k4 >> 1), xf = x0 + (k4 & 1);
      bool valid = (yf >= 0.f) && (yf <= 13.f) && (xf >= 0.f) && (xf <= 13.f);
      int yi = (int)fminf(fmaxf(yf, 0.f), 13.f);
      int xi = (int)fminf(fmaxf(xf, 0.f), 13.f);
      float wgt = ((k4 >> 1) ? wy1 : (1.f - wy1)) * ((k4 & 1) ? wx1 : (1.f - wx1));
      sidx16[t*4 + k4] = (unsigned short)(yi*WW + xi);
      swf[t*4 + k4] = valid ? wgt : 0.f;
    }
  }
  __syncthreads();

  // ---- P1c: bilinear gather -> feats (bf16) ----
  {
    const float* xb = xh + (size_t)b*75264;
    for (int i = t; i < 58*96; i += 256){
      int s = i / 96, c4 = (i - s*96)*4;
      const float* sw = swf + s*4;
      const unsigned short* si = sidx16 + s*4;
      f4 v0 = *(const f4*)(xb + si[0]*384 + c4);
      f4 v1 = *(const f4*)(xb + si[1]*384 + c4);
      f4 v2 = *(const f4*)(xb + si[2]*384 + c4);
      f4 v3 = *(const f4*)(xb + si[3]*384 + c4);
      s4 o;
      #pragma unroll
      for (int j = 0; j < 4; ++j)
        o[j] = bf16r(v0[j]*sw[0] + v1[j]*sw[1] + v2[j]*sw[2] + v3[j]*sw[3]);
      *(s4*)(feats + s*392 + c4) = o;
    }
  }
  __syncthreads();

  // ---- P2: logits D[h][s] = qk_hi·feats + qk_lo·feats (C=0) ----
  {
    f4 acc = {0.f,0.f,0.f,0.f};
    #pragma unroll
    for (int kt = 0; kt < 12; ++kt){
      i4 v0, v1;
      if (kt < 6){ v0 = pf[2*kt]; v1 = pf[2*kt+1]; }
      else { v0 = *(const i4*)(qbase + kt*32); v1 = *(const i4*)(qbase + kt*32 + 4); }
      s8 ah, al;
      #pragma unroll
      for (int j = 0; j < 4; ++j){
        ah[j]   = (short)(v0[j] & 0xffff); al[j]   = (short)(((unsigned)v0[j]) >> 16);
        ah[4+j] = (short)(v1[j] & 0xffff); al[4+j] = (short)(((unsigned)v1[j]) >> 16);
      }
      s8 bfr = *(const s8*)(feats + (w*16 + colh)*392 + kt*32 + quad*8);
      acc = mfma16(ah, bfr, acc);
      acc = mfma16(al, bfr, acc);
    }
    __syncthreads();   // swf/sidx16/qrow dead; scoreS region free
    #pragma unroll
    for (int r = 0; r < 4; ++r){
      int h = quad*4 + r;
      if (h < 12) scoreS[h*64 + w*16 + colh] = acc[r];
    }
  }
  __syncthreads();

  // ---- bias phase: scoreS[h][s] += relpos-bias + qbv[h] ----
  for (int i = t; i < SK*NHEADS; i += 256){
    int s = i / NHEADS, h = i - s*NHEADS;
    float ry, rx;
    if (s < SS){
      int sy = s / RW, sx = s % RW;
      ry = (2.0f*sy - iy)/13.0f - offl[s*2+0];
      rx = (2.0f*sx - ix)/13.0f - offl[s*2+1];
    } else {
      int kk = s - SS;
      ry = colb[kk*2+0] - (float)iy;
      rx = colb[kk*2+1] - (float)ix;
    }
    float py = (ry + 1.0f)*0.5f*26.0f;
    float px = (rx + 1.0f)*0.5f*26.0f;
    float y0 = floorf(py), x0 = floorf(px);
    float wy1 = py - y0, wx1 = px - x0;
    float val = 0.f;
    #pragma unroll
    for (int k4 = 0; k4 < 4; ++k4){
      float yf = y0 + (k4 >> 1), xf = x0 + (k4 & 1);
      if (yf >= 0.f && yf <= 26.f && xf >= 0.f && xf <= 26.f){
        int yi = (int)yf, xi = (int)xf;
        float wgt = ((k4 >> 1) ? wy1 : (1.f - wy1)) * ((k4 & 1) ? wx1 : (1.f - wx1));
        val += pos[(h*TH + yi)*TH + xi] * wgt;
      }
    }
    scoreS[h*64 + s] += val + qbv[h];
  }
  __syncthreads();

  // ---- P3: softmax per head -> attn probs bf16 hi/lo (+ zero pads) ----
  if (t < 192){
    int h = t >> 4, l = t & 15;
    float v[4];
    #pragma unroll
    for (int k = 0; k < 4; ++k){ int s = l + 16*k; v[k] = (s < SK) ? scoreS[h*64 + s] : -1e30f; }
    float mx = fmaxf(fmaxf(v[0], v[1]), fmaxf(v[2], v[3]));
    mx = fmaxf(mx, __shfl_xor(mx, 1)); mx = fmaxf(mx, __shfl_xor(mx, 2));
    mx = fmaxf(mx, __shfl_xor(mx, 4)); mx = fmaxf(mx, __shfl_xor(mx, 8));
    float e[4], sum = 0.f;
    #pragma unroll
    for (int k = 0; k < 4; ++k){ int s = l + 16*k; e[k] = (s < SK) ? expf(v[k] - mx) : 0.f; sum += e[k]; }
    sum += __shfl_xor(sum, 1); sum += __shfl_xor(sum, 2);
    sum += __shfl_xor(sum, 4); sum += __shfl_xor(sum, 8);
    float inv = 1.0f / sum;
    #pragma unroll
    for (int k = 0; k < 4; ++k){
      int s = l + 16*k;
      float p = (s < SK) ? e[k]*inv : 0.f;
      short hi = bf16r(p);
      attnbh[h*72 + s] = hi;
      attnbl[h*72 + s] = bf16r(p - bs2f(hi));
    }
    if (l < 8){ attnbh[h*72 + 64 + l] = 0; attnbl[h*72 + 64 + l] = 0; }
  }
  __syncthreads();

  // ---- P4: fav[h][c] = sum_s attn[h][s]*feats[s][c]; packed int out ----
  {
    s8 a0h = *(const s8*)(attnbh + colh*72 + quad*8);
    s8 a0l = *(const s8*)(attnbl + colh*72 + quad*8);
    s8 a1h = *(const s8*)(attnbh + colh*72 + 32 + quad*8);
    s8 a1l = *(const s8*)(attnbl + colh*72 + 32 + quad*8);
    for (int i = 0; i < 6; ++i){
      int c = (w*6 + i)*16 + colh;
      s8 b0, b1;
      #pragma unroll
      for (int j = 0; j < 8; ++j){
        b0[j] = feats[(quad*8 + j)*392 + c];
        b1[j] = feats[(32 + quad*8 + j)*392 + c];
      }
      f4 acc = {0.f,0.f,0.f,0.f};
      acc = mfma16(a0h, b0, acc);
      acc = mfma16(a0l, b0, acc);
      acc = mfma16(a1h, b1, acc);
      acc = mfma16(a1l, b1, acc);
      #pragma unroll
      for (int r = 0; r < 4; ++r){
        int h = quad*4 + r;
        if (h < 12) favhl[(size_t)blk*4608 + h*384 + c] = packhl(acc[r]);
      }
    }
  }
}

// ---------------- per-head Wv MFMA GEMM: otok[m][h*32+o] = fav_h[m]·Wv_h[o] + bv ----
__global__ void __launch_bounds__(256) k_wv(const int* __restrict__ favhl, const float* __restrict__ Wv,
                                            const float* __restrict__ bv, float* __restrict__ otok){
  __shared__ short Ah[64][40], Al[64][40], Bh[32][40], Bl[32][40];
  int t = threadIdx.x;
  int w = t>>6, lane = t&63, col = lane&15, quad = lane>>4;
  int m0 = blockIdx.x*64; int h = blockIdx.y;
  int r = t>>2, cg = t&3;
  int arow = min(m0 + r, NTOK-1);
  f4 acc[2] = {{0,0,0,0},{0,0,0,0}};
  for (int k0 = 0; k0 < 384; k0 += 32){
    i4 v0 = *(const i4*)(favhl + (size_t)arow*4608 + h*384 + k0 + cg*8);
    i4 v1 = *(const i4*)(favhl + (size_t)arow*4608 + h*384 + k0 + cg*8 + 4);
    s8 ah, al;
    #pragma unroll
    for (int j = 0; j < 4; ++j){
      ah[j]   = (short)(v0[j] & 0xffff); al[j]   = (short)(((unsigned)v0[j]) >> 16);
      ah[4+j] = (short)(v1[j] & 0xffff); al[4+j] = (short)(((unsigned)v1[j]) >> 16);
    }
    s8 bh, bl;
    if (t < 128){
      f4 b0 = *(const f4*)(Wv + (size_t)(h*32 + r)*384 + k0 + cg*8);
      f4 b1 = *(const f4*)(Wv + (size_t)(h*32 + r)*384 + k0 + cg*8 + 4);
      #pragma unroll
      for (int j = 0; j < 4; ++j){
        bh[j] = bf16r(b0[j]); bl[j] = bf16r(b0[j] - bs2f(bh[j]));
        bh[4+j] = bf16r(b1[j]); bl[4+j] = bf16r(b1[j] - bs2f(bh[4+j]));
      }
    }
    __syncthreads();
    *(s8*)&Ah[r][cg*8] = ah; *(s8*)&Al[r][cg*8] = al;
    if (t < 128){ *(s8*)&Bh[r][cg*8] = bh; *(s8*)&Bl[r][cg*8] = bl; }
    __syncthreads();
    s8 afh = *(const s8*)&Ah[w*16+col][quad*8];
    s8 afl = *(const s8*)&Al[w*16+col][quad*8];
    #pragma unroll
    for (int nt = 0; nt < 2; ++nt){
      s8 bfh = *(const s8*)&Bh[nt*16+col][quad*8];
      s8 bfl = *(const s8*)&Bl[nt*16+col][quad*8];
      acc[nt] = mfma16(afh, bfh, acc[nt]);
      acc[nt] = mfma16(afl, bfh, acc[nt]);
      acc[nt] = mfma16(afh, bfl, acc[nt]);
    }
  }
  #pragma unroll
  for (int nt = 0; nt < 2; ++nt){
    #pragma unroll
    for (int rr = 0; rr < 4; ++rr){
      int m = m0 + w*16 + quad*4 + rr;
      if (m < NTOK){
        int o = h*32 + nt*16 + col;
        otok[(size_t)m*384 + o] = acc[nt][rr] + bv[o];
      }
    }
  }
}

extern "C" void kernel_launch(void* const* d_in, const int* in_sizes, int n_in,
                              void* d_out, int out_size, void* d_ws, size_t ws_size,
                              hipStream_t stream){
  const float* x    = (const float*)d_in[0];
  const float* Wq   = (const float*)d_in[1];
  const float* bq   = (const float*)d_in[2];
  const float* Wk   = (const float*)d_in[3];
  const float* bk   = (const float*)d_in[4];
  const float* Wv   = (const float*)d_in[5];
  const float* bv   = (const float*)d_in[6];
  const float* Wo1  = (const float*)d_in[7];
  const float* bo1  = (const float*)d_in[8];
  const float* Wdw  = (const float*)d_in[9];
  const float* bdw  = (const float*)d_in[10];
  const float* ln_g = (const float*)d_in[11];
  const float* ln_b = (const float*)d_in[12];
  const float* Wo2  = (const float*)d_in[13];
  const float* Wco  = (const float*)d_in[14];
  const float* pos  = (const float*)d_in[15];
  const float* Wp   = (const float*)d_in[16];
  const float* bp   = (const float*)d_in[17];
  float* out = (float*)d_out;

  float* ws   = (float*)d_ws;
  float* xh   = ws;                  // 602112 f32
  float* qf   = xh   + 602112;       // 602112
  float* t1   = qf   + 602112;       // 602112
  float* t2   = t1   + 602112;       // 150528
  float* offp = t2   + 150528;       // 153664
  float* otok = offp + 153664;       // 602112
  int*   qkhl = (int*)(otok + 602112);   // 1568*4608 + 2048 pad ints (~28.9 MB)
  int*   favhl = qkhl;               // same-token aliasing: P2 consumes before P4 writes

  k_transpose<<<2352, 256, 0, stream>>>(x, xh);
  k_mmf<0><<<dim3(25,6), 256, 0, stream>>>(xh, Wq,  bq,  qf,   NTOK, 384);
  k_mmf<1><<<dim3(25,6), 256, 0, stream>>>(qf, Wo1, bo1, t1,   NTOK, 384);
  k_dwln<<<392, 384, 0, stream>>>(t1, Wdw, bdw, ln_g, ln_b, t2);
  k_mmf<3><<<dim3(7,7),  256, 0, stream>>>(t2, Wo2, nullptr, offp, 392, 392);
  k_qkp<<<196, 256, 0, stream>>>(qf, Wk, qkhl);
  k_fused<<<1568, 256, 0, stream>>>(xh, qf, offp, qkhl, bk, Wco, pos, favhl);
  k_wv<<<dim3(25,12), 256, 0, stream>>>(favhl, Wv, bv, otok);
  k_mmf<2><<<dim3(25,6), 256, 0, stream>>>(otok, Wp, bp, out, NTOK, 384);
}

// Round 6
// 277.040 us; speedup vs baseline: 3.1968x; 1.0358x over previous
//
#include <hip/hip_runtime.h>
#include <hip/hip_bf16.h>
#include <math.h>

#define BB 8
#define CC 384
#define HH 14
#define WW 14
#define NHEADS 12
#define RH 7
#define RW 7
#define NN 196
#define SS 49
#define KKK 9
#define SK 58
#define TH 27
#define NTOK 1568

typedef float f4 __attribute__((ext_vector_type(4)));
typedef int   i4 __attribute__((ext_vector_type(4)));
typedef short s8 __attribute__((ext_vector_type(8)));
typedef short s4 __attribute__((ext_vector_type(4)));

__device__ __forceinline__ float geluf(float x){ return 0.5f*x*(1.0f+erff(x*0.7071067811865475f)); }
__device__ __forceinline__ short bf16r(float f){
  unsigned u = __float_as_uint(f);
  u += 0x7fff + ((u>>16)&1u);
  return (short)(u>>16);
}
__device__ __forceinline__ float bs2f(short s){ return __uint_as_float(((unsigned)(unsigned short)s)<<16); }
__device__ __forceinline__ int packhl(float v){
  short hi = bf16r(v);
  short lo = bf16r(v - bs2f(hi));
  return (int)((unsigned short)hi | ((unsigned)(unsigned short)lo << 16));
}
__device__ __forceinline__ f4 mfma16(s8 a, s8 b, f4 c){
  return __builtin_amdgcn_mfma_f32_16x16x32_bf16(a, b, c, 0, 0, 0);
}

__constant__ float c_offm[9][2] = {{0,-1},{-1,-1},{-1,0},{-1,1},{0,1},{1,1},{1,0},{1,-1},{0,0}};

// ---------------- transpose B,C,H,W (f32) -> B,H,W,C (f32) ----------------
__global__ void k_transpose(const float* __restrict__ x, float* __restrict__ xh){
  int i = blockIdx.x*256 + threadIdx.x;
  if (i >= BB*HH*WW*CC) return;
  int c = i % CC; int p = i / CC;
  int xx = p % WW; p /= WW;
  int y = p % HH; int b = p / HH;
  xh[i] = x[((b*CC + c)*HH + y)*WW + xx];
}

// ---------------- staged bf16 hi/lo MFMA GEMM, f32 in/out -------------------
// D[m][o] = epi(A[m,:]·W[o,:] + bias[o]); K=384. Tile 64m x 64n.
// EPI: 0 plain, 1 gelu, 2 scatter out[(b*384+o)*196+n], 3 tanh-offset scatter
template<int EPI>
__global__ void __launch_bounds__(256) k_mmf(const float* __restrict__ A, const float* __restrict__ W,
                                             const float* __restrict__ bias, float* __restrict__ out,
                                             int M, int N){
  __shared__ short Ah[64][40], Al[64][40], Bh[64][40], Bl[64][40];
  int t = threadIdx.x;
  int w = t>>6, lane = t&63, col = lane&15, quad = lane>>4;
  int m0 = blockIdx.x*64, n0 = blockIdx.y*64;
  int r = t>>2, cg = t&3;
  int arow = min(m0 + r, M-1);
  int brow = min(n0 + r, N-1);
  f4 acc[4] = {{0,0,0,0},{0,0,0,0},{0,0,0,0},{0,0,0,0}};
  for (int k0 = 0; k0 < 384; k0 += 32){
    f4 a0 = *(const f4*)(A + (size_t)arow*384 + k0 + cg*8);
    f4 a1 = *(const f4*)(A + (size_t)arow*384 + k0 + cg*8 + 4);
    f4 b0 = *(const f4*)(W + (size_t)brow*384 + k0 + cg*8);
    f4 b1 = *(const f4*)(W + (size_t)brow*384 + k0 + cg*8 + 4);
    s8 ah, al, bh, bl;
    #pragma unroll
    for (int j = 0; j < 4; ++j){
      ah[j] = bf16r(a0[j]); al[j] = bf16r(a0[j] - bs2f(ah[j]));
      ah[4+j] = bf16r(a1[j]); al[4+j] = bf16r(a1[j] - bs2f(ah[4+j]));
      bh[j] = bf16r(b0[j]); bl[j] = bf16r(b0[j] - bs2f(bh[j]));
      bh[4+j] = bf16r(b1[j]); bl[4+j] = bf16r(b1[j] - bs2f(bh[4+j]));
    }
    __syncthreads();
    *(s8*)&Ah[r][cg*8] = ah; *(s8*)&Al[r][cg*8] = al;
    *(s8*)&Bh[r][cg*8] = bh; *(s8*)&Bl[r][cg*8] = bl;
    __syncthreads();
    s8 afh = *(const s8*)&Ah[w*16+col][quad*8];
    s8 afl = *(const s8*)&Al[w*16+col][quad*8];
    #pragma unroll
    for (int nt = 0; nt < 4; ++nt){
      s8 bfh = *(const s8*)&Bh[nt*16+col][quad*8];
      s8 bfl = *(const s8*)&Bl[nt*16+col][quad*8];
      acc[nt] = mfma16(afh, bfh, acc[nt]);
      acc[nt] = mfma16(afl, bfh, acc[nt]);
      acc[nt] = mfma16(afh, bfl, acc[nt]);
    }
  }
  #pragma unroll
  for (int nt = 0; nt < 4; ++nt){
    #pragma unroll
    for (int rr = 0; rr < 4; ++rr){
      int m = m0 + w*16 + quad*4 + rr;
      int o = n0 + nt*16 + col;
      if (m >= M || o >= N) continue;
      float v = acc[nt][rr];
      if (EPI == 0){ out[(size_t)m*384 + o] = v + bias[o]; }
      else if (EPI == 1){ out[(size_t)m*384 + o] = geluf(v + bias[o]); }
      else if (EPI == 2){
        int b = m / NN, n = m % NN;
        out[((size_t)b*384 + o)*NN + n] = v + bias[o];
      } else {
        int g = o / NN, nn = o % NN;
        int b = m / SS, s = m % SS;
        float rng = (g == 0) ? (1.0f/HH) : (1.0f/WW);
        out[((b*NN + nn)*SS + s)*2 + g] = tanhf(v) * rng * 2.0f;
      }
    }
  }
}

// ---------------- depthwise 3x3 s2 conv + LN + GELU (f32) -----------------
__global__ void __launch_bounds__(384) k_dwln(const float* __restrict__ t1,
      const float* __restrict__ Wdw, const float* __restrict__ bdw,
      const float* __restrict__ lng, const float* __restrict__ lnb,
      float* __restrict__ t2){
  int blk = blockIdx.x;
  int ow = blk % RW; int oh = (blk / RW) % RH; int b = blk / (RH*RW);
  int c = threadIdx.x;
  float acc = bdw[c];
  #pragma unroll
  for (int kh = 0; kh < 3; ++kh){
    int ih = oh*2 - 1 + kh;
    if (ih < 0 || ih >= HH) continue;
    #pragma unroll
    for (int kw = 0; kw < 3; ++kw){
      int iw = ow*2 - 1 + kw;
      if (iw < 0 || iw >= WW) continue;
      acc += t1[((b*HH + ih)*WW + iw)*CC + c] * Wdw[c*9 + kh*3 + kw];
    }
  }
  __shared__ float red[6];
  __shared__ float s_mu, s_rv;
  float v = acc;
  #pragma unroll
  for (int o = 32; o > 0; o >>= 1) v += __shfl_down(v, o);
  int wid = c >> 6, lane = c & 63;
  if (lane == 0) red[wid] = v;
  __syncthreads();
  if (c == 0){ float s = 0.f; for (int i = 0; i < 6; ++i) s += red[i]; s_mu = s / CC; }
  __syncthreads();
  float mu = s_mu;
  float d = acc - mu;
  v = d*d;
  #pragma unroll
  for (int o = 32; o > 0; o >>= 1) v += __shfl_down(v, o);
  if (lane == 0) red[wid] = v;
  __syncthreads();
  if (c == 0){ float s = 0.f; for (int i = 0; i < 6; ++i) s += red[i]; s_rv = rsqrtf(s / CC + 1e-5f); }
  __syncthreads();
  float val = d * s_rv * lng[c] + lnb[c];
  t2[blk*CC + c] = geluf(val);
}

// ---------------- qk' via hi/lo MFMA: per head, Q_h(1568x32)·Wk_h(32x384) ----
// grid (25 m-tiles, 6 n-tiles, 12 heads); K=32 in one MFMA step
__global__ void __launch_bounds__(256) k_qkp2(const float* __restrict__ qf, const float* __restrict__ Wk,
                                              int* __restrict__ qkhl){
  __shared__ short Ah[64][40], Al[64][40], Bh[64][40], Bl[64][40];
  int t = threadIdx.x;
  int w = t>>6, lane = t&63, col = lane&15, quad = lane>>4;
  int m0 = blockIdx.x*64, n0 = blockIdx.y*64, h = blockIdx.z;
  {
    int r = t>>2, cg = t&3;
    int arow = min(m0 + r, NTOK-1);
    f4 a0 = *(const f4*)(qf + (size_t)arow*384 + h*32 + cg*8);
    f4 a1 = *(const f4*)(qf + (size_t)arow*384 + h*32 + cg*8 + 4);
    s8 ah, al;
    #pragma unroll
    for (int j = 0; j < 4; ++j){
      ah[j] = bf16r(a0[j]); al[j] = bf16r(a0[j] - bs2f(ah[j]));
      ah[4+j] = bf16r(a1[j]); al[4+j] = bf16r(a1[j] - bs2f(ah[4+j]));
    }
    *(s8*)&Ah[r][cg*8] = ah; *(s8*)&Al[r][cg*8] = al;
  }
  // B[c][d] = Wk[h*32+d][n0+c], transposed stage
  for (int i = t; i < 2048; i += 256){
    int d = i >> 6, c = i & 63;
    float v = Wk[(size_t)(h*32 + d)*384 + n0 + c];
    short hi = bf16r(v);
    Bh[c][d] = hi; Bl[c][d] = bf16r(v - bs2f(hi));
  }
  __syncthreads();
  s8 afh = *(const s8*)&Ah[w*16+col][quad*8];
  s8 afl = *(const s8*)&Al[w*16+col][quad*8];
  f4 acc[4] = {{0,0,0,0},{0,0,0,0},{0,0,0,0},{0,0,0,0}};
  #pragma unroll
  for (int nt = 0; nt < 4; ++nt){
    s8 bfh = *(const s8*)&Bh[nt*16+col][quad*8];
    s8 bfl = *(const s8*)&Bl[nt*16+col][quad*8];
    acc[nt] = mfma16(afh, bfh, acc[nt]);
    acc[nt] = mfma16(afl, bfh, acc[nt]);
    acc[nt] = mfma16(afh, bfl, acc[nt]);
  }
  #pragma unroll
  for (int nt = 0; nt < 4; ++nt){
    #pragma unroll
    for (int rr = 0; rr < 4; ++rr){
      int m = m0 + w*16 + quad*4 + rr;
      if (m < NTOK)
        qkhl[(size_t)m*4608 + h*384 + n0 + nt*16 + col] = packhl(acc[nt][rr]);
    }
  }
}

// ---------------- fused per-token attention + Wv projection ----------------
// LDS layout (shorts): feats[58*392] | attnbh[16*72] | attnbl[16*72] | zpad[48]
//   (attnb+zpad region = exactly feats rows 58..63 for P4's k-pad: bf16-safe)
//   after P4, feats region is reused as fav f32 [12][392]
// uni (f32[768]): scoreS[12*64] aliases {qrow[384] | swf[232] | sidx16[232 u16]}
__global__ void __launch_bounds__(256, 3) k_fused(
    const float* __restrict__ xh, const float* __restrict__ qf, const float* __restrict__ off,
    const int* __restrict__ qkhl,
    const float* __restrict__ bk, const float* __restrict__ Wco, const float* __restrict__ pos,
    const float* __restrict__ Wv, const float* __restrict__ bv,
    float* __restrict__ otok){
  __shared__ short smem[25088];
  __shared__ float uni[768];
  __shared__ float offl[98];
  __shared__ float colb[18];
  __shared__ float qbv[12];

  short* feats  = smem;
  short* attnbh = smem + 22736;
  short* attnbl = smem + 23888;
  float* favf   = (float*)smem;   // [12][392] f32, overlays feats after P4
  float* qrow   = uni;
  float* scoreS = uni;            // [12][64], clobbers qrow/swf/sidx16 at P2
  float* swf    = uni + 384;      // [58*4]
  unsigned short* sidx16 = (unsigned short*)(uni + 616); // [58*4]

  int blk = blockIdx.x;
  int n = blk % NN, b = blk / NN;
  int iy = n / WW, ix = n % WW;
  int t = threadIdx.x;
  int w = t>>6, lane = t&63, colh = lane&15, quad = lane>>4;

  // ---- qk prefetch (HBM/L3 latency overlapped with P0/P1) ----
  const int* qbase = qkhl + (size_t)blk*4608 + colh*384 + quad*8;
  i4 pf[12];
  #pragma unroll
  for (int kt = 0; kt < 6; ++kt){
    pf[2*kt]   = *(const i4*)(qbase + kt*32);
    pf[2*kt+1] = *(const i4*)(qbase + kt*32 + 4);
  }

  // ---- P0 ----
  for (int c = t; c < 384; c += 256) qrow[c] = qf[(size_t)blk*384 + c];
  for (int i = t; i < 98; i += 256) offl[i] = off[(size_t)blk*98 + i];
  for (int i = t; i < 2352; i += 256) smem[22736 + i] = 0;   // attnb + zpad
  __syncthreads();

  // ---- P1a: colb (co) and qbv[h]=q_h·bk_h ----
  if (t < 144){
    int o = t >> 3, l = t & 7;
    const float* wr = Wco + o*384 + l*48;
    const float* qr = qrow + l*48;
    f4 a4 = {0.f,0.f,0.f,0.f};
    #pragma unroll
    for (int c = 0; c < 48; c += 4) a4 += (*(const f4*)(qr + c)) * (*(const f4*)(wr + c));
    float acc = a4[0]+a4[1]+a4[2]+a4[3];
    acc += __shfl_xor(acc, 1); acc += __shfl_xor(acc, 2); acc += __shfl_xor(acc, 4);
    if (l == 0){
      int g = o & 1;
      float range = (g == 0) ? (1.0f/HH) : (1.0f/WW);
      colb[o] = tanhf(acc) * range;
    }
  }
  if (t >= 160){
    int o = t - 160;
    int h = o >> 3, l = o & 7;
    float acc = 0.f;
    for (int d = l; d < 32; d += 8) acc += qrow[h*32 + d] * bk[h*32 + d];
    acc += __shfl_xor(acc, 1); acc += __shfl_xor(acc, 2); acc += __shfl_xor(acc, 4);
    if (l == 0 && h < 12) qbv[h] = acc;
  }
  __syncthreads();

  // ---- P1-prep: bilinear corner idx/weights ----
  if (t < SK){
    float cy, cx;
    if (t < SS){
      int sy = t / RW, sx = t % RW;
      cy = offl[t*2+0] + ((2.0f*sy)/13.0f*2.0f - 1.0f);
      cx = offl[t*2+1] + ((2.0f*sx)/13.0f*2.0f - 1.0f);
    } else {
      int kk = t - SS;
      float cyr = fminf(fmaxf((float)iy + c_offm[kk][0], 0.f), (float)HH);
      float cxr = fminf(fmaxf((float)ix + c_offm[kk][1], 0.f), (float)WW);
      cy = colb[kk*2+0] + (cyr/13.0f*2.0f - 1.0f);
      cx = colb[kk*2+1] + (cxr/13.0f*2.0f - 1.0f);
    }
    float py = (cy + 1.0f)*0.5f*13.0f;
    float px = (cx + 1.0f)*0.5f*13.0f;
    float y0 = floorf(py), x0 = floorf(px);
    float wy1 = py - y0, wx1 = px - x0;
    #pragma unroll
    for (int k4 = 0; k4 < 4; ++k4){
      float yf = y0 + (k4 >> 1), xf = x0 + (k4 & 1);
      bool valid = (yf >= 0.f) && (yf <= 13.f) && (xf >= 0.f) && (xf <= 13.f);
      int yi = (int)fminf(fmaxf(yf, 0.f), 13.f);
      int xi = (int)fminf(fmaxf(xf, 0.f), 13.f);
      float wgt = ((k4 >> 1) ? wy1 : (1.f - wy1)) * ((k4 & 1) ? wx1 : (1.f - wx1));
      sidx16[t*4 + k4] = (unsigned short)(yi*WW + xi);
      swf[t*4 + k4] = valid ? wgt : 0.f;
    }
  }
  __syncthreads();

  // ---- P1c: bilinear gather -> feats (bf16) ----
  {
    const float* xb = xh + (size_t)b*75264;
    for (int i = t; i < 58*96; i += 256){
      int s = i / 96, c4 = (i - s*96)*4;
      const float* sw = swf + s*4;
      const unsigned short* si = sidx16 + s*4;
      f4 v0 = *(const f4*)(xb + si[0]*384 + c4);
      f4 v1 = *(const f4*)(xb + si[1]*384 + c4);
      f4 v2 = *(const f4*)(xb + si[2]*384 + c4);
      f4 v3 = *(const f4*)(xb + si[3]*384 + c4);
      s4 o;
      #pragma unroll
      for (int j = 0; j < 4; ++j)
        o[j] = bf16r(v0[j]*sw[0] + v1[j]*sw[1] + v2[j]*sw[2] + v3[j]*sw[3]);
      *(s4*)(feats + s*392 + c4) = o;
    }
  }
  __syncthreads();

  // ---- P2: logits D[h][s] = qk_hi·feats + qk_lo·feats (C=0) ----
  {
    f4 acc = {0.f,0.f,0.f,0.f};
    #pragma unroll
    for (int kt = 0; kt < 12; ++kt){
      i4 v0, v1;
      if (kt < 6){ v0 = pf[2*kt]; v1 = pf[2*kt+1]; }
      else { v0 = *(const i4*)(qbase + kt*32); v1 = *(const i4*)(qbase + kt*32 + 4); }
      s8 ah, al;
      #pragma unroll
      for (int j = 0; j < 4; ++j){
        ah[j]   = (short)(v0[j] & 0xffff); al[j]   = (short)(((unsigned)v0[j]) >> 16);
        ah[4+j] = (short)(v1[j] & 0xffff); al[4+j] = (short)(((unsigned)v1[j]) >> 16);
      }
      s8 bfr = *(const s8*)(feats + (w*16 + colh)*392 + kt*32 + quad*8);
      acc = mfma16(ah, bfr, acc);
      acc = mfma16(al, bfr, acc);
    }
    __syncthreads();   // swf/sidx16/qrow dead; scoreS region free
    #pragma unroll
    for (int r = 0; r < 4; ++r){
      int h = quad*4 + r;
      if (h < 12) scoreS[h*64 + w*16 + colh] = acc[r];
    }
  }
  __syncthreads();

  // ---- bias phase: scoreS[h][s] += relpos-bias + qbv[h] ----
  for (int i = t; i < SK*NHEADS; i += 256){
    int s = i / NHEADS, h = i - s*NHEADS;
    float ry, rx;
    if (s < SS){
      int sy = s / RW, sx = s % RW;
      ry = (2.0f*sy - iy)/13.0f - offl[s*2+0];
      rx = (2.0f*sx - ix)/13.0f - offl[s*2+1];
    } else {
      int kk = s - SS;
      ry = colb[kk*2+0] - (float)iy;
      rx = colb[kk*2+1] - (float)ix;
    }
    float py = (ry + 1.0f)*0.5f*26.0f;
    float px = (rx + 1.0f)*0.5f*26.0f;
    float y0 = floorf(py), x0 = floorf(px);
    float wy1 = py - y0, wx1 = px - x0;
    float val = 0.f;
    #pragma unroll
    for (int k4 = 0; k4 < 4; ++k4){
      float yf = y0 + (k4 >> 1), xf = x0 + (k4 & 1);
      if (yf >= 0.f && yf <= 26.f && xf >= 0.f && xf <= 26.f){
        int yi = (int)yf, xi = (int)xf;
        float wgt = ((k4 >> 1) ? wy1 : (1.f - wy1)) * ((k4 & 1) ? wx1 : (1.f - wx1));
        val += pos[(h*TH + yi)*TH + xi] * wgt;
      }
    }
    scoreS[h*64 + s] += val + qbv[h];
  }
  __syncthreads();

  // ---- P3: softmax per head -> attn probs bf16 hi/lo (+ zero pads) ----
  if (t < 192){
    int h = t >> 4, l = t & 15;
    float v[4];
    #pragma unroll
    for (int k = 0; k < 4; ++k){ int s = l + 16*k; v[k] = (s < SK) ? scoreS[h*64 + s] : -1e30f; }
    float mx = fmaxf(fmaxf(v[0], v[1]), fmaxf(v[2], v[3]));
    mx = fmaxf(mx, __shfl_xor(mx, 1)); mx = fmaxf(mx, __shfl_xor(mx, 2));
    mx = fmaxf(mx, __shfl_xor(mx, 4)); mx = fmaxf(mx, __shfl_xor(mx, 8));
    float e[4], sum = 0.f;
    #pragma unroll
    for (int k = 0; k < 4; ++k){ int s = l + 16*k; e[k] = (s < SK) ? expf(v[k] - mx) : 0.f; sum += e[k]; }
    sum += __shfl_xor(sum, 1); sum += __shfl_xor(sum, 2);
    sum += __shfl_xor(sum, 4); sum += __shfl_xor(sum, 8);
    float inv = 1.0f / sum;
    #pragma unroll
    for (int k = 0; k < 4; ++k){
      int s = l + 16*k;
      float p = (s < SK) ? e[k]*inv : 0.f;
      short hi = bf16r(p);
      attnbh[h*72 + s] = hi;
      attnbl[h*72 + s] = bf16r(p - bs2f(hi));
    }
    if (l < 8){ attnbh[h*72 + 64 + l] = 0; attnbl[h*72 + 64 + l] = 0; }
  }
  __syncthreads();

  // ---- P4: fav[h][c] = sum_s attn[h][s]*feats[s][c] -> registers ----
  f4 facc[6];
  {
    s8 a0h = *(const s8*)(attnbh + colh*72 + quad*8);
    s8 a0l = *(const s8*)(attnbl + colh*72 + quad*8);
    s8 a1h = *(const s8*)(attnbh + colh*72 + 32 + quad*8);
    s8 a1l = *(const s8*)(attnbl + colh*72 + 32 + quad*8);
    #pragma unroll
    for (int i = 0; i < 6; ++i){
      int c = (w*6 + i)*16 + colh;
      s8 b0, b1;
      #pragma unroll
      for (int j = 0; j < 8; ++j){
        b0[j] = feats[(quad*8 + j)*392 + c];
        b1[j] = feats[(32 + quad*8 + j)*392 + c];
      }
      f4 acc = {0.f,0.f,0.f,0.f};
      acc = mfma16(a0h, b0, acc);
      acc = mfma16(a0l, b0, acc);
      acc = mfma16(a1h, b1, acc);
      acc = mfma16(a1l, b1, acc);
      facc[i] = acc;
    }
  }
  __syncthreads();   // all feats reads done; reuse region as fav f32

  #pragma unroll
  for (int i = 0; i < 6; ++i){
    #pragma unroll
    for (int r = 0; r < 4; ++r){
      int h = quad*4 + r;
      if (h < 12) favf[h*392 + (w*6 + i)*16 + colh] = facc[i][r];
    }
  }
  __syncthreads();

  // ---- P5: Wv projection (f32 VALU): otok[o] = fav[h]·Wv[o] + bv[o] ----
  {
    int og = t >> 2, l4 = t & 3;
    #pragma unroll
    for (int p = 0; p < 6; ++p){
      int o = p*64 + og;
      int h = o >> 5;
      const float* wr = Wv + (size_t)o*384;
      const float* fr = favf + h*392;
      f4 a4 = {0.f,0.f,0.f,0.f};
      #pragma unroll
      for (int j = 0; j < 24; ++j){
        int ci = (j*4 + l4)*4;
        a4 += (*(const f4*)(fr + ci)) * (*(const f4*)(wr + ci));
      }
      float acc = a4[0]+a4[1]+a4[2]+a4[3];
      acc += __shfl_xor(acc, 1); acc += __shfl_xor(acc, 2);
      if (l4 == 0) otok[(size_t)blk*384 + o] = acc + bv[o];
    }
  }
}

extern "C" void kernel_launch(void* const* d_in, const int* in_sizes, int n_in,
                              void* d_out, int out_size, void* d_ws, size_t ws_size,
                              hipStream_t stream){
  const float* x    = (const float*)d_in[0];
  const float* Wq   = (const float*)d_in[1];
  const float* bq   = (const float*)d_in[2];
  const float* Wk   = (const float*)d_in[3];
  const float* bk   = (const float*)d_in[4];
  const float* Wv   = (const float*)d_in[5];
  const float* bv   = (const float*)d_in[6];
  const float* Wo1  = (const float*)d_in[7];
  const float* bo1  = (const float*)d_in[8];
  const float* Wdw  = (const float*)d_in[9];
  const float* bdw  = (const float*)d_in[10];
  const float* ln_g = (const float*)d_in[11];
  const float* ln_b = (const float*)d_in[12];
  const float* Wo2  = (const float*)d_in[13];
  const float* Wco  = (const float*)d_in[14];
  const float* pos  = (const float*)d_in[15];
  const float* Wp   = (const float*)d_in[16];
  const float* bp   = (const float*)d_in[17];
  float* out = (float*)d_out;

  float* ws   = (float*)d_ws;
  float* xh   = ws;                  // 602112 f32
  float* qf   = xh   + 602112;       // 602112
  float* t1   = qf   + 602112;       // 602112
  float* t2   = t1   + 602112;       // 150528
  float* offp = t2   + 150528;       // 153664
  float* otok = offp + 153664;       // 602112
  int*   qkhl = (int*)(otok + 602112);   // 1568*4608 + 2048 pad ints (~28.9 MB)

  k_transpose<<<2352, 256, 0, stream>>>(x, xh);
  k_mmf<0><<<dim3(25,6), 256, 0, stream>>>(xh, Wq,  bq,  qf,   NTOK, 384);
  k_mmf<1><<<dim3(25,6), 256, 0, stream>>>(qf, Wo1, bo1, t1,   NTOK, 384);
  k_dwln<<<392, 384, 0, stream>>>(t1, Wdw, bdw, ln_g, ln_b, t2);
  k_mmf<3><<<dim3(7,7),  256, 0, stream>>>(t2, Wo2, nullptr, offp, 392, 392);
  k_qkp2<<<dim3(25,6,12), 256, 0, stream>>>(qf, Wk, qkhl);
  k_fused<<<1568, 256, 0, stream>>>(xh, qf, offp, qkhl, bk, Wco, pos, Wv, bv, otok);
  k_mmf<2><<<dim3(25,6), 256, 0, stream>>>(otok, Wp, bp, out, NTOK, 384);
}

// Round 7
// 261.163 us; speedup vs baseline: 3.3912x; 1.0608x over previous
//
#include <hip/hip_runtime.h>
#include <hip/hip_bf16.h>
#include <math.h>

#define BB 8
#define CC 384
#define HH 14
#define WW 14
#define NHEADS 12
#define RH 7
#define RW 7
#define NN 196
#define SS 49
#define KKK 9
#define SK 58
#define TH 27
#define NTOK 1568

typedef float f4 __attribute__((ext_vector_type(4)));
typedef int   i4 __attribute__((ext_vector_type(4)));
typedef short s8 __attribute__((ext_vector_type(8)));
typedef short s4 __attribute__((ext_vector_type(4)));

__device__ __forceinline__ float geluf(float x){ return 0.5f*x*(1.0f+erff(x*0.7071067811865475f)); }
__device__ __forceinline__ short bf16r(float f){
  unsigned u = __float_as_uint(f);
  u += 0x7fff + ((u>>16)&1u);
  return (short)(u>>16);
}
__device__ __forceinline__ float bs2f(short s){ return __uint_as_float(((unsigned)(unsigned short)s)<<16); }
__device__ __forceinline__ int packhl(float v){
  short hi = bf16r(v);
  short lo = bf16r(v - bs2f(hi));
  return (int)((unsigned short)hi | ((unsigned)(unsigned short)lo << 16));
}
__device__ __forceinline__ f4 mfma16(s8 a, s8 b, f4 c){
  return __builtin_amdgcn_mfma_f32_16x16x32_bf16(a, b, c, 0, 0, 0);
}

__constant__ float c_offm[9][2] = {{0,-1},{-1,-1},{-1,0},{-1,1},{0,1},{1,1},{1,0},{1,-1},{0,0}};

// ---------------- LDS-tiled transpose B,C,H,W -> B,H,W,C (f32) -------------
// grid 64: b = bid>>3, c-tile of 48 = (bid&7)*48
__global__ void __launch_bounds__(256) k_transpose2(const float* __restrict__ x, float* __restrict__ xh){
  __shared__ float tile[48*203];
  int b = blockIdx.x >> 3, c0 = (blockIdx.x & 7)*48;
  int t = threadIdx.x;
  for (int i = t; i < 48*49; i += 256){
    int row = i / 49, seg = i % 49;
    f4 v = *(const f4*)(x + ((size_t)(b*CC + c0 + row))*NN + seg*4);
    #pragma unroll
    for (int j = 0; j < 4; ++j) tile[row*203 + seg*4 + j] = v[j];
  }
  __syncthreads();
  for (int i = t; i < 196*12; i += 256){
    int n = i / 12, seg = i % 12;
    f4 v;
    #pragma unroll
    for (int j = 0; j < 4; ++j) v[j] = tile[(seg*4 + j)*203 + n];
    *(f4*)(xh + ((size_t)(b*NN + n))*CC + c0 + seg*4) = v;
  }
}

// ---------------- staged bf16 hi/lo MFMA GEMM, f32 in/out -------------------
// D[m][o] = epi(A[m,:]·W[o,:] + bias[o]); K=384. Tile 64m x 64n.
// EPI: 0 plain, 1 gelu, 2 coalesced transpose-scatter to out[(b*384+o)*196+n]
template<int EPI>
__global__ void __launch_bounds__(256) k_mmf(const float* __restrict__ A, const float* __restrict__ W,
                                             const float* __restrict__ bias, float* __restrict__ out,
                                             int M, int N){
  __shared__ __align__(16) short sbuf[10240];   // Ah|Al|Bh|Bl each 64x40
  short* Ah = sbuf; short* Al = sbuf + 2560; short* Bh = sbuf + 5120; short* Bl = sbuf + 7680;
  int t = threadIdx.x;
  int w = t>>6, lane = t&63, col = lane&15, quad = lane>>4;
  int m0 = blockIdx.x*64, n0 = blockIdx.y*64;
  int r = t>>2, cg = t&3;
  int arow = min(m0 + r, M-1);
  int brow = min(n0 + r, N-1);
  f4 acc[4] = {{0,0,0,0},{0,0,0,0},{0,0,0,0},{0,0,0,0}};
  for (int k0 = 0; k0 < 384; k0 += 32){
    f4 a0 = *(const f4*)(A + (size_t)arow*384 + k0 + cg*8);
    f4 a1 = *(const f4*)(A + (size_t)arow*384 + k0 + cg*8 + 4);
    f4 b0 = *(const f4*)(W + (size_t)brow*384 + k0 + cg*8);
    f4 b1 = *(const f4*)(W + (size_t)brow*384 + k0 + cg*8 + 4);
    s8 ah, al, bh, bl;
    #pragma unroll
    for (int j = 0; j < 4; ++j){
      ah[j] = bf16r(a0[j]); al[j] = bf16r(a0[j] - bs2f(ah[j]));
      ah[4+j] = bf16r(a1[j]); al[4+j] = bf16r(a1[j] - bs2f(ah[4+j]));
      bh[j] = bf16r(b0[j]); bl[j] = bf16r(b0[j] - bs2f(bh[j]));
      bh[4+j] = bf16r(b1[j]); bl[4+j] = bf16r(b1[j] - bs2f(bh[4+j]));
    }
    __syncthreads();
    *(s8*)(Ah + r*40 + cg*8) = ah; *(s8*)(Al + r*40 + cg*8) = al;
    *(s8*)(Bh + r*40 + cg*8) = bh; *(s8*)(Bl + r*40 + cg*8) = bl;
    __syncthreads();
    s8 afh = *(const s8*)(Ah + (w*16+col)*40 + quad*8);
    s8 afl = *(const s8*)(Al + (w*16+col)*40 + quad*8);
    #pragma unroll
    for (int nt = 0; nt < 4; ++nt){
      s8 bfh = *(const s8*)(Bh + (nt*16+col)*40 + quad*8);
      s8 bfl = *(const s8*)(Bl + (nt*16+col)*40 + quad*8);
      acc[nt] = mfma16(afh, bfh, acc[nt]);
      acc[nt] = mfma16(afl, bfh, acc[nt]);
      acc[nt] = mfma16(afh, bfl, acc[nt]);
    }
  }
  if (EPI == 2){
    float* tile = (float*)sbuf;   // 64 x 65 f32 = 16640 B <= 20480
    __syncthreads();
    #pragma unroll
    for (int nt = 0; nt < 4; ++nt)
      #pragma unroll
      for (int rr = 0; rr < 4; ++rr)
        tile[(w*16 + quad*4 + rr)*65 + nt*16 + col] = acc[nt][rr];
    __syncthreads();
    for (int i = t; i < 1024; i += 256){
      int o_l = i >> 4, ms = i & 15;
      int m = m0 + ms*4;
      if (m >= M) continue;
      int bb = m / NN, nnn = m % NN;   // 196%4==0 and m%4==0 -> no b-crossing in f4
      int o = n0 + o_l;
      float bo = bias[o];
      f4 v = { tile[(ms*4+0)*65 + o_l] + bo, tile[(ms*4+1)*65 + o_l] + bo,
               tile[(ms*4+2)*65 + o_l] + bo, tile[(ms*4+3)*65 + o_l] + bo };
      *(f4*)(out + ((size_t)bb*384 + o)*NN + nnn) = v;
    }
  } else {
    #pragma unroll
    for (int nt = 0; nt < 4; ++nt){
      #pragma unroll
      for (int rr = 0; rr < 4; ++rr){
        int m = m0 + w*16 + quad*4 + rr;
        int o = n0 + nt*16 + col;
        if (m >= M || o >= N) continue;
        float v = acc[nt][rr] + bias[o];
        if (EPI == 1) v = geluf(v);
        out[(size_t)m*384 + o] = v;
      }
    }
  }
}

// ---------------- depthwise 3x3 s2 conv + LN + GELU (f32) -----------------
__global__ void __launch_bounds__(384) k_dwln(const float* __restrict__ t1,
      const float* __restrict__ Wdw, const float* __restrict__ bdw,
      const float* __restrict__ lng, const float* __restrict__ lnb,
      float* __restrict__ t2){
  int blk = blockIdx.x;
  int ow = blk % RW; int oh = (blk / RW) % RH; int b = blk / (RH*RW);
  int c = threadIdx.x;
  float acc = bdw[c];
  #pragma unroll
  for (int kh = 0; kh < 3; ++kh){
    int ih = oh*2 - 1 + kh;
    if (ih < 0 || ih >= HH) continue;
    #pragma unroll
    for (int kw = 0; kw < 3; ++kw){
      int iw = ow*2 - 1 + kw;
      if (iw < 0 || iw >= WW) continue;
      acc += t1[((b*HH + ih)*WW + iw)*CC + c] * Wdw[c*9 + kh*3 + kw];
    }
  }
  __shared__ float red[6];
  __shared__ float s_mu, s_rv;
  float v = acc;
  #pragma unroll
  for (int o = 32; o > 0; o >>= 1) v += __shfl_down(v, o);
  int wid = c >> 6, lane = c & 63;
  if (lane == 0) red[wid] = v;
  __syncthreads();
  if (c == 0){ float s = 0.f; for (int i = 0; i < 6; ++i) s += red[i]; s_mu = s / CC; }
  __syncthreads();
  float mu = s_mu;
  float d = acc - mu;
  v = d*d;
  #pragma unroll
  for (int o = 32; o > 0; o >>= 1) v += __shfl_down(v, o);
  if (lane == 0) red[wid] = v;
  __syncthreads();
  if (c == 0){ float s = 0.f; for (int i = 0; i < 6; ++i) s += red[i]; s_rv = rsqrtf(s / CC + 1e-5f); }
  __syncthreads();
  float val = d * s_rv * lng[c] + lnb[c];
  t2[blk*CC + c] = geluf(val);
}

// ---------------- merged: offset head GEMM (49 blocks) + qk' GEMM (1800) ----
__global__ void __launch_bounds__(256) k_offqk(const float* __restrict__ t2, const float* __restrict__ Wo2,
                                               float* __restrict__ offp,
                                               const float* __restrict__ qf, const float* __restrict__ Wk,
                                               int* __restrict__ qkhl){
  __shared__ __align__(16) short sbuf[10240];
  short* Ah = sbuf; short* Al = sbuf + 2560; short* Bh = sbuf + 5120; short* Bl = sbuf + 7680;
  int t = threadIdx.x;
  int w = t>>6, lane = t&63, col = lane&15, quad = lane>>4;
  int bid = blockIdx.x;

  if (bid < 49){
    // offsets: D = tanh(t2·Wo2^T)*range*2 scattered; M=N=392
    int m0 = (bid/7)*64, n0 = (bid%7)*64;
    int r = t>>2, cg = t&3;
    int arow = min(m0 + r, 391);
    int brow = min(n0 + r, 391);
    f4 acc[4] = {{0,0,0,0},{0,0,0,0},{0,0,0,0},{0,0,0,0}};
    for (int k0 = 0; k0 < 384; k0 += 32){
      f4 a0 = *(const f4*)(t2 + (size_t)arow*384 + k0 + cg*8);
      f4 a1 = *(const f4*)(t2 + (size_t)arow*384 + k0 + cg*8 + 4);
      f4 b0 = *(const f4*)(Wo2 + (size_t)brow*384 + k0 + cg*8);
      f4 b1 = *(const f4*)(Wo2 + (size_t)brow*384 + k0 + cg*8 + 4);
      s8 ah, al, bh, bl;
      #pragma unroll
      for (int j = 0; j < 4; ++j){
        ah[j] = bf16r(a0[j]); al[j] = bf16r(a0[j] - bs2f(ah[j]));
        ah[4+j] = bf16r(a1[j]); al[4+j] = bf16r(a1[j] - bs2f(ah[4+j]));
        bh[j] = bf16r(b0[j]); bl[j] = bf16r(b0[j] - bs2f(bh[j]));
        bh[4+j] = bf16r(b1[j]); bl[4+j] = bf16r(b1[j] - bs2f(bh[4+j]));
      }
      __syncthreads();
      *(s8*)(Ah + r*40 + cg*8) = ah; *(s8*)(Al + r*40 + cg*8) = al;
      *(s8*)(Bh + r*40 + cg*8) = bh; *(s8*)(Bl + r*40 + cg*8) = bl;
      __syncthreads();
      s8 afh = *(const s8*)(Ah + (w*16+col)*40 + quad*8);
      s8 afl = *(const s8*)(Al + (w*16+col)*40 + quad*8);
      #pragma unroll
      for (int nt = 0; nt < 4; ++nt){
        s8 bfh = *(const s8*)(Bh + (nt*16+col)*40 + quad*8);
        s8 bfl = *(const s8*)(Bl + (nt*16+col)*40 + quad*8);
        acc[nt] = mfma16(afh, bfh, acc[nt]);
        acc[nt] = mfma16(afl, bfh, acc[nt]);
        acc[nt] = mfma16(afh, bfl, acc[nt]);
      }
    }
    #pragma unroll
    for (int nt = 0; nt < 4; ++nt){
      #pragma unroll
      for (int rr = 0; rr < 4; ++rr){
        int row = m0 + w*16 + quad*4 + rr;
        int o = n0 + nt*16 + col;
        if (row < 392 && o < 392){
          int g = o / NN, nn = o % NN;
          int b = row / SS, s = row % SS;
          float rng = (g == 0) ? (1.0f/HH) : (1.0f/WW);
          offp[((b*NN + nn)*SS + s)*2 + g] = tanhf(acc[nt][rr]) * rng * 2.0f;
        }
      }
    }
  } else {
    // qk': per head h, Q_h(1568x32)·Wk_h(32x384), packed hi|lo ints
    int idx = bid - 49;
    int m0 = (idx % 25)*64, n0 = ((idx/25) % 6)*64, h = idx/150;
    {
      int r = t>>2, cg = t&3;
      int arow = min(m0 + r, NTOK-1);
      f4 a0 = *(const f4*)(qf + (size_t)arow*384 + h*32 + cg*8);
      f4 a1 = *(const f4*)(qf + (size_t)arow*384 + h*32 + cg*8 + 4);
      s8 ah, al;
      #pragma unroll
      for (int j = 0; j < 4; ++j){
        ah[j] = bf16r(a0[j]); al[j] = bf16r(a0[j] - bs2f(ah[j]));
        ah[4+j] = bf16r(a1[j]); al[4+j] = bf16r(a1[j] - bs2f(ah[4+j]));
      }
      *(s8*)(Ah + r*40 + cg*8) = ah; *(s8*)(Al + r*40 + cg*8) = al;
    }
    for (int i = t; i < 2048; i += 256){
      int d = i >> 6, c = i & 63;
      float v = Wk[(size_t)(h*32 + d)*384 + n0 + c];
      short hi = bf16r(v);
      Bh[c*40 + d] = hi; Bl[c*40 + d] = bf16r(v - bs2f(hi));
    }
    __syncthreads();
    s8 afh = *(const s8*)(Ah + (w*16+col)*40 + quad*8);
    s8 afl = *(const s8*)(Al + (w*16+col)*40 + quad*8);
    f4 acc[4] = {{0,0,0,0},{0,0,0,0},{0,0,0,0},{0,0,0,0}};
    #pragma unroll
    for (int nt = 0; nt < 4; ++nt){
      s8 bfh = *(const s8*)(Bh + (nt*16+col)*40 + quad*8);
      s8 bfl = *(const s8*)(Bl + (nt*16+col)*40 + quad*8);
      acc[nt] = mfma16(afh, bfh, acc[nt]);
      acc[nt] = mfma16(afl, bfh, acc[nt]);
      acc[nt] = mfma16(afh, bfl, acc[nt]);
    }
    #pragma unroll
    for (int nt = 0; nt < 4; ++nt){
      #pragma unroll
      for (int rr = 0; rr < 4; ++rr){
        int m = m0 + w*16 + quad*4 + rr;
        if (m < NTOK)
          qkhl[(size_t)m*4608 + h*384 + n0 + nt*16 + col] = packhl(acc[nt][rr]);
      }
    }
  }
}

// ---------------- fused per-token attention --------------------------------
// fav (single bf16) overlays first half of the token's consumed qk region.
__global__ void __launch_bounds__(256, 3) k_fused(
    const float* __restrict__ xh, const float* __restrict__ qf, const float* __restrict__ off,
    const int* __restrict__ qkhl,
    const float* __restrict__ bk, const float* __restrict__ Wco, const float* __restrict__ pos,
    short* __restrict__ favS){
  __shared__ short smem[25088];
  __shared__ float uni[768];
  __shared__ float offl[98];
  __shared__ float colb[18];
  __shared__ float qbv[12];

  short* feats  = smem;
  short* attnbh = smem + 22736;
  short* attnbl = smem + 23888;
  float* qrow   = uni;
  float* scoreS = uni;            // [12][64], clobbers qrow/swf/sidx16 at P2
  float* swf    = uni + 384;      // [58*4]
  unsigned short* sidx16 = (unsigned short*)(uni + 616); // [58*4]

  int blk = blockIdx.x;
  int n = blk % NN, b = blk / NN;
  int iy = n / WW, ix = n % WW;
  int t = threadIdx.x;
  int w = t>>6, lane = t&63, colh = lane&15, quad = lane>>4;

  // ---- qk full prefetch (HBM latency overlapped with P0..P1c) ----
  const int* qbase = qkhl + (size_t)blk*4608 + colh*384 + quad*8;
  i4 pf[24];
  #pragma unroll
  for (int kt = 0; kt < 12; ++kt){
    pf[2*kt]   = *(const i4*)(qbase + kt*32);
    pf[2*kt+1] = *(const i4*)(qbase + kt*32 + 4);
  }

  // ---- P0 ----
  for (int c = t; c < 384; c += 256) qrow[c] = qf[(size_t)blk*384 + c];
  for (int i = t; i < 98; i += 256) offl[i] = off[(size_t)blk*98 + i];
  for (int i = t; i < 2352; i += 256) smem[22736 + i] = 0;
  __syncthreads();

  // ---- P1a: colb (co) and qbv[h]=q_h·bk_h ----
  if (t < 144){
    int o = t >> 3, l = t & 7;
    const float* wr = Wco + o*384 + l*48;
    const float* qr = qrow + l*48;
    f4 a4 = {0.f,0.f,0.f,0.f};
    #pragma unroll
    for (int c = 0; c < 48; c += 4) a4 += (*(const f4*)(qr + c)) * (*(const f4*)(wr + c));
    float acc = a4[0]+a4[1]+a4[2]+a4[3];
    acc += __shfl_xor(acc, 1); acc += __shfl_xor(acc, 2); acc += __shfl_xor(acc, 4);
    if (l == 0){
      int g = o & 1;
      float range = (g == 0) ? (1.0f/HH) : (1.0f/WW);
      colb[o] = tanhf(acc) * range;
    }
  }
  if (t >= 160){
    int o = t - 160;
    int h = o >> 3, l = o & 7;
    float acc = 0.f;
    for (int d = l; d < 32; d += 8) acc += qrow[h*32 + d] * bk[h*32 + d];
    acc += __shfl_xor(acc, 1); acc += __shfl_xor(acc, 2); acc += __shfl_xor(acc, 4);
    if (l == 0 && h < 12) qbv[h] = acc;
  }
  __syncthreads();

  // ---- P1-prep: bilinear corner idx/weights ----
  if (t < SK){
    float cy, cx;
    if (t < SS){
      int sy = t / RW, sx = t % RW;
      cy = offl[t*2+0] + ((2.0f*sy)/13.0f*2.0f - 1.0f);
      cx = offl[t*2+1] + ((2.0f*sx)/13.0f*2.0f - 1.0f);
    } else {
      int kk = t - SS;
      float cyr = fminf(fmaxf((float)iy + c_offm[kk][0], 0.f), (float)HH);
      float cxr = fminf(fmaxf((float)ix + c_offm[kk][1], 0.f), (float)WW);
      cy = colb[kk*2+0] + (cyr/13.0f*2.0f - 1.0f);
      cx = colb[kk*2+1] + (cxr/13.0f*2.0f - 1.0f);
    }
    float py = (cy + 1.0f)*0.5f*13.0f;
    float px = (cx + 1.0f)*0.5f*13.0f;
    float y0 = floorf(py), x0 = floorf(px);
    float wy1 = py - y0, wx1 = px - x0;
    #pragma unroll
    for (int k4 = 0; k4 < 4; ++k4){
      float yf = y0 + (k4 >> 1), xf = x0 + (k4 & 1);
      bool valid = (yf >= 0.f) && (yf <= 13.f) && (xf >= 0.f) && (xf <= 13.f);
      int yi = (int)fminf(fmaxf(yf, 0.f), 13.f);
      int xi = (int)fminf(fmaxf(xf, 0.f), 13.f);
      float wgt = ((k4 >> 1) ? wy1 : (1.f - wy1)) * ((k4 & 1) ? wx1 : (1.f - wx1));
      sidx16[t*4 + k4] = (unsigned short)(yi*WW + xi);
      swf[t*4 + k4] = valid ? wgt : 0.f;
    }
  }
  __syncthreads();

  // ---- P1c: bilinear gather -> feats (bf16) ----
  {
    const float* xb = xh + (size_t)b*75264;
    for (int i = t; i < 58*96; i += 256){
      int s = i / 96, c4 = (i - s*96)*4;
      const float* sw = swf + s*4;
      const unsigned short* si = sidx16 + s*4;
      f4 v0 = *(const f4*)(xb + si[0]*384 + c4);
      f4 v1 = *(const f4*)(xb + si[1]*384 + c4);
      f4 v2 = *(const f4*)(xb + si[2]*384 + c4);
      f4 v3 = *(const f4*)(xb + si[3]*384 + c4);
      s4 o;
      #pragma unroll
      for (int j = 0; j < 4; ++j)
        o[j] = bf16r(v0[j]*sw[0] + v1[j]*sw[1] + v2[j]*sw[2] + v3[j]*sw[3]);
      *(s4*)(feats + s*392 + c4) = o;
    }
  }
  __syncthreads();

  // ---- P2: logits D[h][s] = qk_hi·feats + qk_lo·feats (C=0) ----
  {
    f4 acc = {0.f,0.f,0.f,0.f};
    #pragma unroll
    for (int kt = 0; kt < 12; ++kt){
      i4 v0 = pf[2*kt], v1 = pf[2*kt+1];
      s8 ah, al;
      #pragma unroll
      for (int j = 0; j < 4; ++j){
        ah[j]   = (short)(v0[j] & 0xffff); al[j]   = (short)(((unsigned)v0[j]) >> 16);
        ah[4+j] = (short)(v1[j] & 0xffff); al[4+j] = (short)(((unsigned)v1[j]) >> 16);
      }
      s8 bfr = *(const s8*)(feats + (w*16 + colh)*392 + kt*32 + quad*8);
      acc = mfma16(ah, bfr, acc);
      acc = mfma16(al, bfr, acc);
    }
    __syncthreads();
    #pragma unroll
    for (int r = 0; r < 4; ++r){
      int h = quad*4 + r;
      if (h < 12) scoreS[h*64 + w*16 + colh] = acc[r];
    }
  }
  __syncthreads();

  // ---- bias phase: scoreS[h][s] += relpos-bias + qbv[h] ----
  for (int i = t; i < SK*NHEADS; i += 256){
    int s = i / NHEADS, h = i - s*NHEADS;
    float ry, rx;
    if (s < SS){
      int sy = s / RW, sx = s % RW;
      ry = (2.0f*sy - iy)/13.0f - offl[s*2+0];
      rx = (2.0f*sx - ix)/13.0f - offl[s*2+1];
    } else {
      int kk = s - SS;
      ry = colb[kk*2+0] - (float)iy;
      rx = colb[kk*2+1] - (float)ix;
    }
    float py = (ry + 1.0f)*0.5f*26.0f;
    float px = (rx + 1.0f)*0.5f*26.0f;
    float y0 = floorf(py), x0 = floorf(px);
    float wy1 = py - y0, wx1 = px - x0;
    float val = 0.f;
    #pragma unroll
    for (int k4 = 0; k4 < 4; ++k4){
      float yf = y0 + (k4 >> 1), xf = x0 + (k4 & 1);
      if (yf >= 0.f && yf <= 26.f && xf >= 0.f && xf <= 26.f){
        int yi = (int)yf, xi = (int)xf;
        float wgt = ((k4 >> 1) ? wy1 : (1.f - wy1)) * ((k4 & 1) ? wx1 : (1.f - wx1));
        val += pos[(h*TH + yi)*TH + xi] * wgt;
      }
    }
    scoreS[h*64 + s] += val + qbv[h];
  }
  __syncthreads();

  // ---- P3: softmax per head -> attn probs bf16 hi/lo (+ zero pads) ----
  if (t < 192){
    int h = t >> 4, l = t & 15;
    float v[4];
    #pragma unroll
    for (int k = 0; k < 4; ++k){ int s = l + 16*k; v[k] = (s < SK) ? scoreS[h*64 + s] : -1e30f; }
    float mx = fmaxf(fmaxf(v[0], v[1]), fmaxf(v[2], v[3]));
    mx = fmaxf(mx, __shfl_xor(mx, 1)); mx = fmaxf(mx, __shfl_xor(mx, 2));
    mx = fmaxf(mx, __shfl_xor(mx, 4)); mx = fmaxf(mx, __shfl_xor(mx, 8));
    float e[4], sum = 0.f;
    #pragma unroll
    for (int k = 0; k < 4; ++k){ int s = l + 16*k; e[k] = (s < SK) ? expf(v[k] - mx) : 0.f; sum += e[k]; }
    sum += __shfl_xor(sum, 1); sum += __shfl_xor(sum, 2);
    sum += __shfl_xor(sum, 4); sum += __shfl_xor(sum, 8);
    float inv = 1.0f / sum;
    #pragma unroll
    for (int k = 0; k < 4; ++k){
      int s = l + 16*k;
      float p = (s < SK) ? e[k]*inv : 0.f;
      short hi = bf16r(p);
      attnbh[h*72 + s] = hi;
      attnbl[h*72 + s] = bf16r(p - bs2f(hi));
    }
    if (l < 8){ attnbh[h*72 + 64 + l] = 0; attnbl[h*72 + 64 + l] = 0; }
  }
  __syncthreads();

  // ---- P4: fav[h][c] = sum_s attn[h][s]*feats[s][c]; single-bf16 out ----
  {
    s8 a0h = *(const s8*)(attnbh + colh*72 + quad*8);
    s8 a0l = *(const s8*)(attnbl + colh*72 + quad*8);
    s8 a1h = *(const s8*)(attnbh + colh*72 + 32 + quad*8);
    s8 a1l = *(const s8*)(attnbl + colh*72 + 32 + quad*8);
    #pragma unroll
    for (int i = 0; i < 6; ++i){
      int c = (w*6 + i)*16 + colh;
      s8 b0, b1;
      #pragma unroll
      for (int j = 0; j < 8; ++j){
        b0[j] = feats[(quad*8 + j)*392 + c];
        b1[j] = feats[(32 + quad*8 + j)*392 + c];
      }
      f4 acc = {0.f,0.f,0.f,0.f};
      acc = mfma16(a0h, b0, acc);
      acc = mfma16(a0l, b0, acc);
      acc = mfma16(a1h, b1, acc);
      acc = mfma16(a1l, b1, acc);
      #pragma unroll
      for (int r = 0; r < 4; ++r){
        int h = quad*4 + r;
        if (h < 12) favS[(size_t)blk*9216 + h*384 + c] = bf16r(acc[r]);
      }
    }
  }
}

// ---------------- per-head Wv MFMA GEMM (no LDS): otok = fav_h·Wv_h + bv ----
__global__ void __launch_bounds__(256) k_wv(const short* __restrict__ favS, const float* __restrict__ Wv,
                                            const float* __restrict__ bv, float* __restrict__ otok){
  int t = threadIdx.x;
  int w = t>>6, lane = t&63, col = lane&15, quad = lane>>4;
  int m0 = blockIdx.x*64; int h = blockIdx.y;
  int arow = min(m0 + w*16 + col, NTOK-1);
  f4 acc[2] = {{0,0,0,0},{0,0,0,0}};
  for (int k0 = 0; k0 < 384; k0 += 32){
    s8 af = *(const s8*)(favS + (size_t)arow*9216 + h*384 + k0 + quad*8);
    #pragma unroll
    for (int nt = 0; nt < 2; ++nt){
      int orow = h*32 + nt*16 + col;
      f4 b0 = *(const f4*)(Wv + (size_t)orow*384 + k0 + quad*8);
      f4 b1 = *(const f4*)(Wv + (size_t)orow*384 + k0 + quad*8 + 4);
      s8 bh, bl;
      #pragma unroll
      for (int j = 0; j < 4; ++j){
        bh[j] = bf16r(b0[j]); bl[j] = bf16r(b0[j] - bs2f(bh[j]));
        bh[4+j] = bf16r(b1[j]); bl[4+j] = bf16r(b1[j] - bs2f(bh[4+j]));
      }
      acc[nt] = mfma16(af, bh, acc[nt]);
      acc[nt] = mfma16(af, bl, acc[nt]);
    }
  }
  #pragma unroll
  for (int nt = 0; nt < 2; ++nt){
    #pragma unroll
    for (int rr = 0; rr < 4; ++rr){
      int m = m0 + w*16 + quad*4 + rr;
      if (m < NTOK){
        int o = h*32 + nt*16 + col;
        otok[(size_t)m*384 + o] = acc[nt][rr] + bv[o];
      }
    }
  }
}

extern "C" void kernel_launch(void* const* d_in, const int* in_sizes, int n_in,
                              void* d_out, int out_size, void* d_ws, size_t ws_size,
                              hipStream_t stream){
  const float* x    = (const float*)d_in[0];
  const float* Wq   = (const float*)d_in[1];
  const float* bq   = (const float*)d_in[2];
  const float* Wk   = (const float*)d_in[3];
  const float* bk   = (const float*)d_in[4];
  const float* Wv   = (const float*)d_in[5];
  const float* bv   = (const float*)d_in[6];
  const float* Wo1  = (const float*)d_in[7];
  const float* bo1  = (const float*)d_in[8];
  const float* Wdw  = (const float*)d_in[9];
  const float* bdw  = (const float*)d_in[10];
  const float* ln_g = (const float*)d_in[11];
  const float* ln_b = (const float*)d_in[12];
  const float* Wo2  = (const float*)d_in[13];
  const float* Wco  = (const float*)d_in[14];
  const float* pos  = (const float*)d_in[15];
  const float* Wp   = (const float*)d_in[16];
  const float* bp   = (const float*)d_in[17];
  float* out = (float*)d_out;

  float* ws   = (float*)d_ws;
  float* xh   = ws;                  // 602112 f32
  float* qf   = xh   + 602112;
  float* t1   = qf   + 602112;
  float* t2   = t1   + 602112;       // 150528
  float* offp = t2   + 150528;       // 153664
  float* otok = offp + 153664;       // 602112
  int*   qkhl = (int*)(otok + 602112);   // 1568*4608 ints (+pad)
  short* favS = (short*)qkhl;        // fav[blk] = first 4608 shorts of blk's 9216-short qk region
                                     // (safe: P2 reads blk's qk before P4 writes blk's fav)

  k_transpose2<<<64, 256, 0, stream>>>(x, xh);
  k_mmf<0><<<dim3(25,6), 256, 0, stream>>>(xh, Wq,  bq,  qf, NTOK, 384);
  k_mmf<1><<<dim3(25,6), 256, 0, stream>>>(qf, Wo1, bo1, t1, NTOK, 384);
  k_dwln<<<392, 384, 0, stream>>>(t1, Wdw, bdw, ln_g, ln_b, t2);
  k_offqk<<<1849, 256, 0, stream>>>(t2, Wo2, offp, qf, Wk, qkhl);
  k_fused<<<1568, 256, 0, stream>>>(xh, qf, offp, qkhl, bk, Wco, pos, favS);
  k_wv<<<dim3(25,12), 256, 0, stream>>>(favS, Wv, bv, otok);
  k_mmf<2><<<dim3(25,6), 256, 0, stream>>>(otok, Wp, bp, out, NTOK, 384);
}

// Round 8
// 254.748 us; speedup vs baseline: 3.4766x; 1.0252x over previous
//
#include <hip/hip_runtime.h>
#include <hip/hip_bf16.h>
#include <math.h>

#define BB 8
#define CC 384
#define HH 14
#define WW 14
#define NHEADS 12
#define RH 7
#define RW 7
#define NN 196
#define SS 49
#define KKK 9
#define SK 58
#define TH 27
#define NTOK 1568

typedef float f4 __attribute__((ext_vector_type(4)));
typedef int   i4 __attribute__((ext_vector_type(4)));
typedef short s8 __attribute__((ext_vector_type(8)));
typedef short s4 __attribute__((ext_vector_type(4)));

__device__ __forceinline__ float geluf(float x){ return 0.5f*x*(1.0f+erff(x*0.7071067811865475f)); }
__device__ __forceinline__ short bf16r(float f){
  unsigned u = __float_as_uint(f);
  u += 0x7fff + ((u>>16)&1u);
  return (short)(u>>16);
}
__device__ __forceinline__ float bs2f(short s){ return __uint_as_float(((unsigned)(unsigned short)s)<<16); }
__device__ __forceinline__ int packhl(float v){
  short hi = bf16r(v);
  short lo = bf16r(v - bs2f(hi));
  return (int)((unsigned short)hi | ((unsigned)(unsigned short)lo << 16));
}
__device__ __forceinline__ f4 mfma16(s8 a, s8 b, f4 c){
  return __builtin_amdgcn_mfma_f32_16x16x32_bf16(a, b, c, 0, 0, 0);
}

__constant__ float c_offm[9][2] = {{0,-1},{-1,-1},{-1,0},{-1,1},{0,1},{1,1},{1,0},{1,-1},{0,0}};

// ---------------- LDS-tiled transpose B,C,H,W -> B,H,W,C (f32) -------------
__global__ void __launch_bounds__(256) k_transpose2(const float* __restrict__ x, float* __restrict__ xh){
  __shared__ float tile[48*203];
  int b = blockIdx.x >> 3, c0 = (blockIdx.x & 7)*48;
  int t = threadIdx.x;
  for (int i = t; i < 48*49; i += 256){
    int row = i / 49, seg = i % 49;
    f4 v = *(const f4*)(x + ((size_t)(b*CC + c0 + row))*NN + seg*4);
    #pragma unroll
    for (int j = 0; j < 4; ++j) tile[row*203 + seg*4 + j] = v[j];
  }
  __syncthreads();
  for (int i = t; i < 196*12; i += 256){
    int n = i / 12, seg = i % 12;
    f4 v;
    #pragma unroll
    for (int j = 0; j < 4; ++j) v[j] = tile[(seg*4 + j)*203 + n];
    *(f4*)(xh + ((size_t)(b*NN + n))*CC + c0 + seg*4) = v;
  }
}

// ---------------- staged bf16 hi/lo MFMA GEMM, f32 in/out -------------------
template<int EPI>
__global__ void __launch_bounds__(256) k_mmf(const float* __restrict__ A, const float* __restrict__ W,
                                             const float* __restrict__ bias, float* __restrict__ out,
                                             int M, int N){
  __shared__ __align__(16) short sbuf[10240];
  short* Ah = sbuf; short* Al = sbuf + 2560; short* Bh = sbuf + 5120; short* Bl = sbuf + 7680;
  int t = threadIdx.x;
  int w = t>>6, lane = t&63, col = lane&15, quad = lane>>4;
  int m0 = blockIdx.x*64, n0 = blockIdx.y*64;
  int r = t>>2, cg = t&3;
  int arow = min(m0 + r, M-1);
  int brow = min(n0 + r, N-1);
  f4 acc[4] = {{0,0,0,0},{0,0,0,0},{0,0,0,0},{0,0,0,0}};
  for (int k0 = 0; k0 < 384; k0 += 32){
    f4 a0 = *(const f4*)(A + (size_t)arow*384 + k0 + cg*8);
    f4 a1 = *(const f4*)(A + (size_t)arow*384 + k0 + cg*8 + 4);
    f4 b0 = *(const f4*)(W + (size_t)brow*384 + k0 + cg*8);
    f4 b1 = *(const f4*)(W + (size_t)brow*384 + k0 + cg*8 + 4);
    s8 ah, al, bh, bl;
    #pragma unroll
    for (int j = 0; j < 4; ++j){
      ah[j] = bf16r(a0[j]); al[j] = bf16r(a0[j] - bs2f(ah[j]));
      ah[4+j] = bf16r(a1[j]); al[4+j] = bf16r(a1[j] - bs2f(ah[4+j]));
      bh[j] = bf16r(b0[j]); bl[j] = bf16r(b0[j] - bs2f(bh[j]));
      bh[4+j] = bf16r(b1[j]); bl[4+j] = bf16r(b1[j] - bs2f(bh[4+j]));
    }
    __syncthreads();
    *(s8*)(Ah + r*40 + cg*8) = ah; *(s8*)(Al + r*40 + cg*8) = al;
    *(s8*)(Bh + r*40 + cg*8) = bh; *(s8*)(Bl + r*40 + cg*8) = bl;
    __syncthreads();
    s8 afh = *(const s8*)(Ah + (w*16+col)*40 + quad*8);
    s8 afl = *(const s8*)(Al + (w*16+col)*40 + quad*8);
    #pragma unroll
    for (int nt = 0; nt < 4; ++nt){
      s8 bfh = *(const s8*)(Bh + (nt*16+col)*40 + quad*8);
      s8 bfl = *(const s8*)(Bl + (nt*16+col)*40 + quad*8);
      acc[nt] = mfma16(afh, bfh, acc[nt]);
      acc[nt] = mfma16(afl, bfh, acc[nt]);
      acc[nt] = mfma16(afh, bfl, acc[nt]);
    }
  }
  if (EPI == 2){
    float* tile = (float*)sbuf;
    __syncthreads();
    #pragma unroll
    for (int nt = 0; nt < 4; ++nt)
      #pragma unroll
      for (int rr = 0; rr < 4; ++rr)
        tile[(w*16 + quad*4 + rr)*65 + nt*16 + col] = acc[nt][rr];
    __syncthreads();
    for (int i = t; i < 1024; i += 256){
      int o_l = i >> 4, ms = i & 15;
      int m = m0 + ms*4;
      if (m >= M) continue;
      int bb = m / NN, nnn = m % NN;
      int o = n0 + o_l;
      float bo = bias[o];
      f4 v = { tile[(ms*4+0)*65 + o_l] + bo, tile[(ms*4+1)*65 + o_l] + bo,
               tile[(ms*4+2)*65 + o_l] + bo, tile[(ms*4+3)*65 + o_l] + bo };
      *(f4*)(out + ((size_t)bb*384 + o)*NN + nnn) = v;
    }
  } else {
    #pragma unroll
    for (int nt = 0; nt < 4; ++nt){
      #pragma unroll
      for (int rr = 0; rr < 4; ++rr){
        int m = m0 + w*16 + quad*4 + rr;
        int o = n0 + nt*16 + col;
        if (m >= M || o >= N) continue;
        float v = acc[nt][rr] + bias[o];
        if (EPI == 1) v = geluf(v);
        out[(size_t)m*384 + o] = v;
      }
    }
  }
}

// ---------------- depthwise 3x3 s2 conv + LN + GELU (f32) -----------------
__global__ void __launch_bounds__(384) k_dwln(const float* __restrict__ t1,
      const float* __restrict__ Wdw, const float* __restrict__ bdw,
      const float* __restrict__ lng, const float* __restrict__ lnb,
      float* __restrict__ t2){
  int blk = blockIdx.x;
  int ow = blk % RW; int oh = (blk / RW) % RH; int b = blk / (RH*RW);
  int c = threadIdx.x;
  float acc = bdw[c];
  #pragma unroll
  for (int kh = 0; kh < 3; ++kh){
    int ih = oh*2 - 1 + kh;
    if (ih < 0 || ih >= HH) continue;
    #pragma unroll
    for (int kw = 0; kw < 3; ++kw){
      int iw = ow*2 - 1 + kw;
      if (iw < 0 || iw >= WW) continue;
      acc += t1[((b*HH + ih)*WW + iw)*CC + c] * Wdw[c*9 + kh*3 + kw];
    }
  }
  __shared__ float red[6];
  __shared__ float s_mu, s_rv;
  float v = acc;
  #pragma unroll
  for (int o = 32; o > 0; o >>= 1) v += __shfl_down(v, o);
  int wid = c >> 6, lane = c & 63;
  if (lane == 0) red[wid] = v;
  __syncthreads();
  if (c == 0){ float s = 0.f; for (int i = 0; i < 6; ++i) s += red[i]; s_mu = s / CC; }
  __syncthreads();
  float mu = s_mu;
  float d = acc - mu;
  v = d*d;
  #pragma unroll
  for (int o = 32; o > 0; o >>= 1) v += __shfl_down(v, o);
  if (lane == 0) red[wid] = v;
  __syncthreads();
  if (c == 0){ float s = 0.f; for (int i = 0; i < 6; ++i) s += red[i]; s_rv = rsqrtf(s / CC + 1e-5f); }
  __syncthreads();
  float val = d * s_rv * lng[c] + lnb[c];
  t2[blk*CC + c] = geluf(val);
}

// ---------------- merged: offset head GEMM (49 blocks) + qk' GEMM (1800) ----
__global__ void __launch_bounds__(256) k_offqk(const float* __restrict__ t2, const float* __restrict__ Wo2,
                                               float* __restrict__ offp,
                                               const float* __restrict__ qf, const float* __restrict__ Wk,
                                               int* __restrict__ qkhl){
  __shared__ __align__(16) short sbuf[10240];
  short* Ah = sbuf; short* Al = sbuf + 2560; short* Bh = sbuf + 5120; short* Bl = sbuf + 7680;
  int t = threadIdx.x;
  int w = t>>6, lane = t&63, col = lane&15, quad = lane>>4;
  int bid = blockIdx.x;

  if (bid < 49){
    int m0 = (bid/7)*64, n0 = (bid%7)*64;
    int r = t>>2, cg = t&3;
    int arow = min(m0 + r, 391);
    int brow = min(n0 + r, 391);
    f4 acc[4] = {{0,0,0,0},{0,0,0,0},{0,0,0,0},{0,0,0,0}};
    for (int k0 = 0; k0 < 384; k0 += 32){
      f4 a0 = *(const f4*)(t2 + (size_t)arow*384 + k0 + cg*8);
      f4 a1 = *(const f4*)(t2 + (size_t)arow*384 + k0 + cg*8 + 4);
      f4 b0 = *(const f4*)(Wo2 + (size_t)brow*384 + k0 + cg*8);
      f4 b1 = *(const f4*)(Wo2 + (size_t)brow*384 + k0 + cg*8 + 4);
      s8 ah, al, bh, bl;
      #pragma unroll
      for (int j = 0; j < 4; ++j){
        ah[j] = bf16r(a0[j]); al[j] = bf16r(a0[j] - bs2f(ah[j]));
        ah[4+j] = bf16r(a1[j]); al[4+j] = bf16r(a1[j] - bs2f(ah[4+j]));
        bh[j] = bf16r(b0[j]); bl[j] = bf16r(b0[j] - bs2f(bh[j]));
        bh[4+j] = bf16r(b1[j]); bl[4+j] = bf16r(b1[j] - bs2f(bh[4+j]));
      }
      __syncthreads();
      *(s8*)(Ah + r*40 + cg*8) = ah; *(s8*)(Al + r*40 + cg*8) = al;
      *(s8*)(Bh + r*40 + cg*8) = bh; *(s8*)(Bl + r*40 + cg*8) = bl;
      __syncthreads();
      s8 afh = *(const s8*)(Ah + (w*16+col)*40 + quad*8);
      s8 afl = *(const s8*)(Al + (w*16+col)*40 + quad*8);
      #pragma unroll
      for (int nt = 0; nt < 4; ++nt){
        s8 bfh = *(const s8*)(Bh + (nt*16+col)*40 + quad*8);
        s8 bfl = *(const s8*)(Bl + (nt*16+col)*40 + quad*8);
        acc[nt] = mfma16(afh, bfh, acc[nt]);
        acc[nt] = mfma16(afl, bfh, acc[nt]);
        acc[nt] = mfma16(afh, bfl, acc[nt]);
      }
    }
    #pragma unroll
    for (int nt = 0; nt < 4; ++nt){
      #pragma unroll
      for (int rr = 0; rr < 4; ++rr){
        int row = m0 + w*16 + quad*4 + rr;
        int o = n0 + nt*16 + col;
        if (row < 392 && o < 392){
          int g = o / NN, nn = o % NN;
          int b = row / SS, s = row % SS;
          float rng = (g == 0) ? (1.0f/HH) : (1.0f/WW);
          offp[((b*NN + nn)*SS + s)*2 + g] = tanhf(acc[nt][rr]) * rng * 2.0f;
        }
      }
    }
  } else {
    int idx = bid - 49;
    int m0 = (idx % 25)*64, n0 = ((idx/25) % 6)*64, h = idx/150;
    {
      int r = t>>2, cg = t&3;
      int arow = min(m0 + r, NTOK-1);
      f4 a0 = *(const f4*)(qf + (size_t)arow*384 + h*32 + cg*8);
      f4 a1 = *(const f4*)(qf + (size_t)arow*384 + h*32 + cg*8 + 4);
      s8 ah, al;
      #pragma unroll
      for (int j = 0; j < 4; ++j){
        ah[j] = bf16r(a0[j]); al[j] = bf16r(a0[j] - bs2f(ah[j]));
        ah[4+j] = bf16r(a1[j]); al[4+j] = bf16r(a1[j] - bs2f(ah[4+j]));
      }
      *(s8*)(Ah + r*40 + cg*8) = ah; *(s8*)(Al + r*40 + cg*8) = al;
    }
    for (int i = t; i < 2048; i += 256){
      int d = i >> 6, c = i & 63;
      float v = Wk[(size_t)(h*32 + d)*384 + n0 + c];
      short hi = bf16r(v);
      Bh[c*40 + d] = hi; Bl[c*40 + d] = bf16r(v - bs2f(hi));
    }
    __syncthreads();
    s8 afh = *(const s8*)(Ah + (w*16+col)*40 + quad*8);
    s8 afl = *(const s8*)(Al + (w*16+col)*40 + quad*8);
    f4 acc[4] = {{0,0,0,0},{0,0,0,0},{0,0,0,0},{0,0,0,0}};
    #pragma unroll
    for (int nt = 0; nt < 4; ++nt){
      s8 bfh = *(const s8*)(Bh + (nt*16+col)*40 + quad*8);
      s8 bfl = *(const s8*)(Bl + (nt*16+col)*40 + quad*8);
      acc[nt] = mfma16(afh, bfh, acc[nt]);
      acc[nt] = mfma16(afl, bfh, acc[nt]);
      acc[nt] = mfma16(afh, bfl, acc[nt]);
    }
    #pragma unroll
    for (int nt = 0; nt < 4; ++nt){
      #pragma unroll
      for (int rr = 0; rr < 4; ++rr){
        int m = m0 + w*16 + quad*4 + rr;
        if (m < NTOK)
          qkhl[(size_t)m*4608 + h*384 + n0 + nt*16 + col] = packhl(acc[nt][rr]);
      }
    }
  }
}

// ---------------- fused per-token attention --------------------------------
// launch_bounds(256,2): LDS caps at 2 blocks/CU anyway; 256-VGPR budget keeps
// the 96-VGPR qk prefetch resident (R7: (256,3) made the compiler sink it).
__global__ void __launch_bounds__(256, 2) k_fused(
    const float* __restrict__ xh, const float* __restrict__ qf, const float* __restrict__ off,
    const int* __restrict__ qkhl,
    const float* __restrict__ bk, const float* __restrict__ Wco, const float* __restrict__ pos,
    short* __restrict__ favS){
  __shared__ short smem[25088];
  __shared__ float uni[768];
  __shared__ float biasf[768];    // [12..16][64] bias+qbv, written in gather phase
  __shared__ float offl[98];
  __shared__ float colb[18];
  __shared__ float qbv[12];

  short* feats  = smem;
  short* attnbh = smem + 22736;
  short* attnbl = smem + 23888;
  float* qrow   = uni;
  float* scoreS = uni;            // [12][64], clobbers qrow/swf/sidx16 at P2
  float* swf    = uni + 384;
  unsigned short* sidx16 = (unsigned short*)(uni + 616);

  int blk = blockIdx.x;
  int n = blk % NN, b = blk / NN;
  int iy = n / WW, ix = n % WW;
  int t = threadIdx.x;
  int w = t>>6, lane = t&63, colh = lane&15, quad = lane>>4;

  // ---- qk full prefetch; head index clamped (lanes 12-15 dup lane 11's lines) ----
  int hclamp = min(colh, 11);
  const int* qbase = qkhl + (size_t)blk*4608 + hclamp*384 + quad*8;
  i4 pf[24];
  #pragma unroll
  for (int kt = 0; kt < 12; ++kt){
    pf[2*kt]   = *(const i4*)(qbase + kt*32);
    pf[2*kt+1] = *(const i4*)(qbase + kt*32 + 4);
  }

  // ---- P0 ----
  for (int c = t; c < 384; c += 256) qrow[c] = qf[(size_t)blk*384 + c];
  for (int i = t; i < 98; i += 256) offl[i] = off[(size_t)blk*98 + i];
  for (int i = t; i < 2352; i += 256) smem[22736 + i] = 0;
  __syncthreads();

  // ---- P1a: colb (co) and qbv[h]=q_h·bk_h ----
  if (t < 144){
    int o = t >> 3, l = t & 7;
    const float* wr = Wco + o*384 + l*48;
    const float* qr = qrow + l*48;
    f4 a4 = {0.f,0.f,0.f,0.f};
    #pragma unroll
    for (int c = 0; c < 48; c += 4) a4 += (*(const f4*)(qr + c)) * (*(const f4*)(wr + c));
    float acc = a4[0]+a4[1]+a4[2]+a4[3];
    acc += __shfl_xor(acc, 1); acc += __shfl_xor(acc, 2); acc += __shfl_xor(acc, 4);
    if (l == 0){
      int g = o & 1;
      float range = (g == 0) ? (1.0f/HH) : (1.0f/WW);
      colb[o] = tanhf(acc) * range;
    }
  }
  if (t >= 160){
    int o = t - 160;
    int h = o >> 3, l = o & 7;
    float acc = 0.f;
    for (int d = l; d < 32; d += 8) acc += qrow[h*32 + d] * bk[h*32 + d];
    acc += __shfl_xor(acc, 1); acc += __shfl_xor(acc, 2); acc += __shfl_xor(acc, 4);
    if (l == 0 && h < 12) qbv[h] = acc;
  }
  __syncthreads();

  // ---- P1-prep: bilinear corner idx/weights ----
  if (t < SK){
    float cy, cx;
    if (t < SS){
      int sy = t / RW, sx = t % RW;
      cy = offl[t*2+0] + ((2.0f*sy)/13.0f*2.0f - 1.0f);
      cx = offl[t*2+1] + ((2.0f*sx)/13.0f*2.0f - 1.0f);
    } else {
      int kk = t - SS;
      float cyr = fminf(fmaxf((float)iy + c_offm[kk][0], 0.f), (float)HH);
      float cxr = fminf(fmaxf((float)ix + c_offm[kk][1], 0.f), (float)WW);
      cy = colb[kk*2+0] + (cyr/13.0f*2.0f - 1.0f);
      cx = colb[kk*2+1] + (cxr/13.0f*2.0f - 1.0f);
    }
    float py = (cy + 1.0f)*0.5f*13.0f;
    float px = (cx + 1.0f)*0.5f*13.0f;
    float y0 = floorf(py), x0 = floorf(px);
    float wy1 = py - y0, wx1 = px - x0;
    #pragma unroll
    for (int k4 = 0; k4 < 4; ++k4){
      float yf = y0 + (k4 >> 1), xf = x0 + (k4 & 1);
      bool valid = (yf >= 0.f) && (yf <= 13.f) && (xf >= 0.f) && (xf <= 13.f);
      int yi = (int)fminf(fmaxf(yf, 0.f), 13.f);
      int xi = (int)fminf(fmaxf(xf, 0.f), 13.f);
      float wgt = ((k4 >> 1) ? wy1 : (1.f - wy1)) * ((k4 & 1) ? wx1 : (1.f - wx1));
      sidx16[t*4 + k4] = (unsigned short)(yi*WW + xi);
      swf[t*4 + k4] = valid ? wgt : 0.f;
    }
  }
  __syncthreads();

  // ---- merged phase: bilinear gather -> feats  +  rel-pos bias -> biasf ----
  {
    const float* xb = xh + (size_t)b*75264;
    for (int i = t; i < 58*96; i += 256){
      int s = i / 96, c4 = (i - s*96)*4;
      const float* sw = swf + s*4;
      const unsigned short* si = sidx16 + s*4;
      f4 v0 = *(const f4*)(xb + si[0]*384 + c4);
      f4 v1 = *(const f4*)(xb + si[1]*384 + c4);
      f4 v2 = *(const f4*)(xb + si[2]*384 + c4);
      f4 v3 = *(const f4*)(xb + si[3]*384 + c4);
      s4 o;
      #pragma unroll
      for (int j = 0; j < 4; ++j)
        o[j] = bf16r(v0[j]*sw[0] + v1[j]*sw[1] + v2[j]*sw[2] + v3[j]*sw[3]);
      *(s4*)(feats + s*392 + c4) = o;
    }
    for (int i = t; i < SK*NHEADS; i += 256){
      int s = i / NHEADS, h = i - s*NHEADS;
      float ry, rx;
      if (s < SS){
        int sy = s / RW, sx = s % RW;
        ry = (2.0f*sy - iy)/13.0f - offl[s*2+0];
        rx = (2.0f*sx - ix)/13.0f - offl[s*2+1];
      } else {
        int kk = s - SS;
        ry = colb[kk*2+0] - (float)iy;
        rx = colb[kk*2+1] - (float)ix;
      }
      float py = (ry + 1.0f)*0.5f*26.0f;
      float px = (rx + 1.0f)*0.5f*26.0f;
      float y0 = floorf(py), x0 = floorf(px);
      float wy1 = py - y0, wx1 = px - x0;
      float val = 0.f;
      #pragma unroll
      for (int k4 = 0; k4 < 4; ++k4){
        float yf = y0 + (k4 >> 1), xf = x0 + (k4 & 1);
        if (yf >= 0.f && yf <= 26.f && xf >= 0.f && xf <= 26.f){
          int yi = (int)yf, xi = (int)xf;
          float wgt = ((k4 >> 1) ? wy1 : (1.f - wy1)) * ((k4 & 1) ? wx1 : (1.f - wx1));
          val += pos[(h*TH + yi)*TH + xi] * wgt;
        }
      }
      biasf[h*64 + s] = val + qbv[h];
    }
  }
  __syncthreads();

  // ---- P2: logits D[h][s] = qk_hi·feats + qk_lo·feats, C-init = biasf ----
  {
    f4 acc;
    #pragma unroll
    for (int r = 0; r < 4; ++r){
      int h = quad*4 + r;
      int s = w*16 + colh;
      acc[r] = (h < 12 && s < SK) ? biasf[h*64 + s] : 0.f;
    }
    #pragma unroll
    for (int kt = 0; kt < 12; ++kt){
      i4 v0 = pf[2*kt], v1 = pf[2*kt+1];
      s8 ah, al;
      #pragma unroll
      for (int j = 0; j < 4; ++j){
        ah[j]   = (short)(v0[j] & 0xffff); al[j]   = (short)(((unsigned)v0[j]) >> 16);
        ah[4+j] = (short)(v1[j] & 0xffff); al[4+j] = (short)(((unsigned)v1[j]) >> 16);
      }
      s8 bfr = *(const s8*)(feats + (w*16 + colh)*392 + kt*32 + quad*8);
      acc = mfma16(ah, bfr, acc);
      acc = mfma16(al, bfr, acc);
    }
    __syncthreads();   // qrow/swf/sidx dead -> scoreS region free
    #pragma unroll
    for (int r = 0; r < 4; ++r){
      int h = quad*4 + r;
      if (h < 12) scoreS[h*64 + w*16 + colh] = acc[r];
    }
  }
  __syncthreads();

  // ---- P3: softmax per head -> attn probs bf16 hi/lo (+ zero pads) ----
  if (t < 192){
    int h = t >> 4, l = t & 15;
    float v[4];
    #pragma unroll
    for (int k = 0; k < 4; ++k){ int s = l + 16*k; v[k] = (s < SK) ? scoreS[h*64 + s] : -1e30f; }
    float mx = fmaxf(fmaxf(v[0], v[1]), fmaxf(v[2], v[3]));
    mx = fmaxf(mx, __shfl_xor(mx, 1)); mx = fmaxf(mx, __shfl_xor(mx, 2));
    mx = fmaxf(mx, __shfl_xor(mx, 4)); mx = fmaxf(mx, __shfl_xor(mx, 8));
    float e[4], sum = 0.f;
    #pragma unroll
    for (int k = 0; k < 4; ++k){ int s = l + 16*k; e[k] = (s < SK) ? expf(v[k] - mx) : 0.f; sum += e[k]; }
    sum += __shfl_xor(sum, 1); sum += __shfl_xor(sum, 2);
    sum += __shfl_xor(sum, 4); sum += __shfl_xor(sum, 8);
    float inv = 1.0f / sum;
    #pragma unroll
    for (int k = 0; k < 4; ++k){
      int s = l + 16*k;
      float p = (s < SK) ? e[k]*inv : 0.f;
      short hi = bf16r(p);
      attnbh[h*72 + s] = hi;
      attnbl[h*72 + s] = bf16r(p - bs2f(hi));
    }
    if (l < 8){ attnbh[h*72 + 64 + l] = 0; attnbl[h*72 + 64 + l] = 0; }
  }
  __syncthreads();

  // ---- P4: fav[h][c] = sum_s attn[h][s]*feats[s][c]; single-bf16 out ----
  {
    s8 a0h = *(const s8*)(attnbh + colh*72 + quad*8);
    s8 a0l = *(const s8*)(attnbl + colh*72 + quad*8);
    s8 a1h = *(const s8*)(attnbh + colh*72 + 32 + quad*8);
    s8 a1l = *(const s8*)(attnbl + colh*72 + 32 + quad*8);
    #pragma unroll
    for (int i = 0; i < 6; ++i){
      int c = (w*6 + i)*16 + colh;
      s8 b0, b1;
      #pragma unroll
      for (int j = 0; j < 8; ++j){
        b0[j] = feats[(quad*8 + j)*392 + c];
        b1[j] = feats[(32 + quad*8 + j)*392 + c];
      }
      f4 acc = {0.f,0.f,0.f,0.f};
      acc = mfma16(a0h, b0, acc);
      acc = mfma16(a0l, b0, acc);
      acc = mfma16(a1h, b1, acc);
      acc = mfma16(a1l, b1, acc);
      #pragma unroll
      for (int r = 0; r < 4; ++r){
        int h = quad*4 + r;
        if (h < 12) favS[(size_t)blk*9216 + h*384 + c] = bf16r(acc[r]);
      }
    }
  }
}

// ---------------- per-head Wv MFMA GEMM (no LDS): otok = fav_h·Wv_h + bv ----
__global__ void __launch_bounds__(256) k_wv(const short* __restrict__ favS, const float* __restrict__ Wv,
                                            const float* __restrict__ bv, float* __restrict__ otok){
  int t = threadIdx.x;
  int w = t>>6, lane = t&63, col = lane&15, quad = lane>>4;
  int m0 = blockIdx.x*64; int h = blockIdx.y;
  int arow = min(m0 + w*16 + col, NTOK-1);
  f4 acc[2] = {{0,0,0,0},{0,0,0,0}};
  for (int k0 = 0; k0 < 384; k0 += 32){
    s8 af = *(const s8*)(favS + (size_t)arow*9216 + h*384 + k0 + quad*8);
    #pragma unroll
    for (int nt = 0; nt < 2; ++nt){
      int orow = h*32 + nt*16 + col;
      f4 b0 = *(const f4*)(Wv + (size_t)orow*384 + k0 + quad*8);
      f4 b1 = *(const f4*)(Wv + (size_t)orow*384 + k0 + quad*8 + 4);
      s8 bh, bl;
      #pragma unroll
      for (int j = 0; j < 4; ++j){
        bh[j] = bf16r(b0[j]); bl[j] = bf16r(b0[j] - bs2f(bh[j]));
        bh[4+j] = bf16r(b1[j]); bl[4+j] = bf16r(b1[j] - bs2f(bh[4+j]));
      }
      acc[nt] = mfma16(af, bh, acc[nt]);
      acc[nt] = mfma16(af, bl, acc[nt]);
    }
  }
  #pragma unroll
  for (int nt = 0; nt < 2; ++nt){
    #pragma unroll
    for (int rr = 0; rr < 4; ++rr){
      int m = m0 + w*16 + quad*4 + rr;
      if (m < NTOK){
        int o = h*32 + nt*16 + col;
        otok[(size_t)m*384 + o] = acc[nt][rr] + bv[o];
      }
    }
  }
}

extern "C" void kernel_launch(void* const* d_in, const int* in_sizes, int n_in,
                              void* d_out, int out_size, void* d_ws, size_t ws_size,
                              hipStream_t stream){
  const float* x    = (const float*)d_in[0];
  const float* Wq   = (const float*)d_in[1];
  const float* bq   = (const float*)d_in[2];
  const float* Wk   = (const float*)d_in[3];
  const float* bk   = (const float*)d_in[4];
  const float* Wv   = (const float*)d_in[5];
  const float* bv   = (const float*)d_in[6];
  const float* Wo1  = (const float*)d_in[7];
  const float* bo1  = (const float*)d_in[8];
  const float* Wdw  = (const float*)d_in[9];
  const float* bdw  = (const float*)d_in[10];
  const float* ln_g = (const float*)d_in[11];
  const float* ln_b = (const float*)d_in[12];
  const float* Wo2  = (const float*)d_in[13];
  const float* Wco  = (const float*)d_in[14];
  const float* pos  = (const float*)d_in[15];
  const float* Wp   = (const float*)d_in[16];
  const float* bp   = (const float*)d_in[17];
  float* out = (float*)d_out;

  float* ws   = (float*)d_ws;
  float* xh   = ws;
  float* qf   = xh   + 602112;
  float* t1   = qf   + 602112;
  float* t2   = t1   + 602112;
  float* offp = t2   + 150528;
  float* otok = offp + 153664;
  int*   qkhl = (int*)(otok + 602112);
  short* favS = (short*)qkhl;

  k_transpose2<<<64, 256, 0, stream>>>(x, xh);
  k_mmf<0><<<dim3(25,6), 256, 0, stream>>>(xh, Wq,  bq,  qf, NTOK, 384);
  k_mmf<1><<<dim3(25,6), 256, 0, stream>>>(qf, Wo1, bo1, t1, NTOK, 384);
  k_dwln<<<392, 384, 0, stream>>>(t1, Wdw, bdw, ln_g, ln_b, t2);
  k_offqk<<<1849, 256, 0, stream>>>(t2, Wo2, offp, qf, Wk, qkhl);
  k_fused<<<1568, 256, 0, stream>>>(xh, qf, offp, qkhl, bk, Wco, pos, favS);
  k_wv<<<dim3(25,12), 256, 0, stream>>>(favS, Wv, bv, otok);
  k_mmf<2><<<dim3(25,6), 256, 0, stream>>>(otok, Wp, bp, out, NTOK, 384);
}

// Round 9
// 241.740 us; speedup vs baseline: 3.6637x; 1.0538x over previous
//
#include <hip/hip_runtime.h>
#include <hip/hip_bf16.h>
#include <math.h>

#define BB 8
#define CC 384
#define HH 14
#define WW 14
#define NHEADS 12
#define RH 7
#define RW 7
#define NN 196
#define SS 49
#define KKK 9
#define SK 58
#define TH 27
#define NTOK 1568

typedef float    f4 __attribute__((ext_vector_type(4)));
typedef _Float16 h8 __attribute__((ext_vector_type(8)));
typedef _Float16 h4 __attribute__((ext_vector_type(4)));

__device__ __forceinline__ float geluf(float x){ return 0.5f*x*(1.0f+erff(x*0.7071067811865475f)); }
__device__ __forceinline__ f4 mfma16h(h8 a, h8 b, f4 c){
  return __builtin_amdgcn_mfma_f32_16x16x32_f16(a, b, c, 0, 0, 0);
}

__constant__ float c_offm[9][2] = {{0,-1},{-1,-1},{-1,0},{-1,1},{0,1},{1,1},{1,0},{1,-1},{0,0}};

// ---------------- LDS-tiled transpose B,C,H,W -> B,H,W,C (f32) -------------
__global__ void __launch_bounds__(256) k_transpose2(const float* __restrict__ x, float* __restrict__ xh){
  __shared__ float tile[48*203];
  int b = blockIdx.x >> 3, c0 = (blockIdx.x & 7)*48;
  int t = threadIdx.x;
  for (int i = t; i < 48*49; i += 256){
    int row = i / 49, seg = i % 49;
    f4 v = *(const f4*)(x + ((size_t)(b*CC + c0 + row))*NN + seg*4);
    #pragma unroll
    for (int j = 0; j < 4; ++j) tile[row*203 + seg*4 + j] = v[j];
  }
  __syncthreads();
  for (int i = t; i < 196*12; i += 256){
    int n = i / 12, seg = i % 12;
    f4 v;
    #pragma unroll
    for (int j = 0; j < 4; ++j) v[j] = tile[(seg*4 + j)*203 + n];
    *(f4*)(xh + ((size_t)(b*NN + n))*CC + c0 + seg*4) = v;
  }
}

// ---------------- staged fp16 hi/lo MFMA GEMM, f32 in/out -------------------
// EPI: 0 plain, 1 gelu, 2 coalesced transpose-scatter to out[(b*384+o)*196+n]
template<int EPI>
__global__ void __launch_bounds__(256) k_mmf(const float* __restrict__ A, const float* __restrict__ W,
                                             const float* __restrict__ bias, float* __restrict__ out,
                                             int M, int N){
  __shared__ __align__(16) _Float16 sbuf[10240];
  _Float16* Ah = sbuf; _Float16* Al = sbuf + 2560; _Float16* Bh = sbuf + 5120; _Float16* Bl = sbuf + 7680;
  int t = threadIdx.x;
  int w = t>>6, lane = t&63, col = lane&15, quad = lane>>4;
  int m0 = blockIdx.x*64, n0 = blockIdx.y*64;
  int r = t>>2, cg = t&3;
  int arow = min(m0 + r, M-1);
  int brow = min(n0 + r, N-1);
  f4 acc[4] = {{0,0,0,0},{0,0,0,0},{0,0,0,0},{0,0,0,0}};
  for (int k0 = 0; k0 < 384; k0 += 32){
    f4 a0 = *(const f4*)(A + (size_t)arow*384 + k0 + cg*8);
    f4 a1 = *(const f4*)(A + (size_t)arow*384 + k0 + cg*8 + 4);
    f4 b0 = *(const f4*)(W + (size_t)brow*384 + k0 + cg*8);
    f4 b1 = *(const f4*)(W + (size_t)brow*384 + k0 + cg*8 + 4);
    h8 ah, al, bh, bl;
    #pragma unroll
    for (int j = 0; j < 4; ++j){
      ah[j] = (_Float16)a0[j];   al[j] = (_Float16)(a0[j] - (float)ah[j]);
      ah[4+j] = (_Float16)a1[j]; al[4+j] = (_Float16)(a1[j] - (float)ah[4+j]);
      bh[j] = (_Float16)b0[j];   bl[j] = (_Float16)(b0[j] - (float)bh[j]);
      bh[4+j] = (_Float16)b1[j]; bl[4+j] = (_Float16)(b1[j] - (float)bh[4+j]);
    }
    __syncthreads();
    *(h8*)(Ah + r*40 + cg*8) = ah; *(h8*)(Al + r*40 + cg*8) = al;
    *(h8*)(Bh + r*40 + cg*8) = bh; *(h8*)(Bl + r*40 + cg*8) = bl;
    __syncthreads();
    h8 afh = *(const h8*)(Ah + (w*16+col)*40 + quad*8);
    h8 afl = *(const h8*)(Al + (w*16+col)*40 + quad*8);
    #pragma unroll
    for (int nt = 0; nt < 4; ++nt){
      h8 bfh = *(const h8*)(Bh + (nt*16+col)*40 + quad*8);
      h8 bfl = *(const h8*)(Bl + (nt*16+col)*40 + quad*8);
      acc[nt] = mfma16h(afh, bfh, acc[nt]);
      acc[nt] = mfma16h(afl, bfh, acc[nt]);
      acc[nt] = mfma16h(afh, bfl, acc[nt]);
    }
  }
  if (EPI == 2){
    float* tile = (float*)sbuf;
    __syncthreads();
    #pragma unroll
    for (int nt = 0; nt < 4; ++nt)
      #pragma unroll
      for (int rr = 0; rr < 4; ++rr)
        tile[(w*16 + quad*4 + rr)*65 + nt*16 + col] = acc[nt][rr];
    __syncthreads();
    for (int i = t; i < 1024; i += 256){
      int o_l = i >> 4, ms = i & 15;
      int m = m0 + ms*4;
      if (m >= M) continue;
      int bb = m / NN, nnn = m % NN;
      int o = n0 + o_l;
      float bo = bias[o];
      f4 v = { tile[(ms*4+0)*65 + o_l] + bo, tile[(ms*4+1)*65 + o_l] + bo,
               tile[(ms*4+2)*65 + o_l] + bo, tile[(ms*4+3)*65 + o_l] + bo };
      *(f4*)(out + ((size_t)bb*384 + o)*NN + nnn) = v;
    }
  } else {
    #pragma unroll
    for (int nt = 0; nt < 4; ++nt){
      #pragma unroll
      for (int rr = 0; rr < 4; ++rr){
        int m = m0 + w*16 + quad*4 + rr;
        int o = n0 + nt*16 + col;
        if (m >= M || o >= N) continue;
        float v = acc[nt][rr] + bias[o];
        if (EPI == 1) v = geluf(v);
        out[(size_t)m*384 + o] = v;
      }
    }
  }
}

// ---------------- depthwise 3x3 s2 conv + LN + GELU (f32) -----------------
__global__ void __launch_bounds__(384) k_dwln(const float* __restrict__ t1,
      const float* __restrict__ Wdw, const float* __restrict__ bdw,
      const float* __restrict__ lng, const float* __restrict__ lnb,
      float* __restrict__ t2){
  int blk = blockIdx.x;
  int ow = blk % RW; int oh = (blk / RW) % RH; int b = blk / (RH*RW);
  int c = threadIdx.x;
  float acc = bdw[c];
  #pragma unroll
  for (int kh = 0; kh < 3; ++kh){
    int ih = oh*2 - 1 + kh;
    if (ih < 0 || ih >= HH) continue;
    #pragma unroll
    for (int kw = 0; kw < 3; ++kw){
      int iw = ow*2 - 1 + kw;
      if (iw < 0 || iw >= WW) continue;
      acc += t1[((b*HH + ih)*WW + iw)*CC + c] * Wdw[c*9 + kh*3 + kw];
    }
  }
  __shared__ float red[6];
  __shared__ float s_mu, s_rv;
  float v = acc;
  #pragma unroll
  for (int o = 32; o > 0; o >>= 1) v += __shfl_down(v, o);
  int wid = c >> 6, lane = c & 63;
  if (lane == 0) red[wid] = v;
  __syncthreads();
  if (c == 0){ float s = 0.f; for (int i = 0; i < 6; ++i) s += red[i]; s_mu = s / CC; }
  __syncthreads();
  float mu = s_mu;
  float d = acc - mu;
  v = d*d;
  #pragma unroll
  for (int o = 32; o > 0; o >>= 1) v += __shfl_down(v, o);
  if (lane == 0) red[wid] = v;
  __syncthreads();
  if (c == 0){ float s = 0.f; for (int i = 0; i < 6; ++i) s += red[i]; s_rv = rsqrtf(s / CC + 1e-5f); }
  __syncthreads();
  float val = d * s_rv * lng[c] + lnb[c];
  t2[blk*CC + c] = geluf(val);
}

// ---------------- merged: offset head GEMM (49 blocks) + qk' GEMM (1800) ----
// qk' output: SINGLE fp16 (fp16's 11-bit mantissa suffices for logits)
__global__ void __launch_bounds__(256) k_offqk(const float* __restrict__ t2, const float* __restrict__ Wo2,
                                               float* __restrict__ offp,
                                               const float* __restrict__ qf, const float* __restrict__ Wk,
                                               _Float16* __restrict__ qkh){
  __shared__ __align__(16) _Float16 sbuf[10240];
  _Float16* Ah = sbuf; _Float16* Al = sbuf + 2560; _Float16* Bh = sbuf + 5120; _Float16* Bl = sbuf + 7680;
  int t = threadIdx.x;
  int w = t>>6, lane = t&63, col = lane&15, quad = lane>>4;
  int bid = blockIdx.x;

  if (bid < 49){
    int m0 = (bid/7)*64, n0 = (bid%7)*64;
    int r = t>>2, cg = t&3;
    int arow = min(m0 + r, 391);
    int brow = min(n0 + r, 391);
    f4 acc[4] = {{0,0,0,0},{0,0,0,0},{0,0,0,0},{0,0,0,0}};
    for (int k0 = 0; k0 < 384; k0 += 32){
      f4 a0 = *(const f4*)(t2 + (size_t)arow*384 + k0 + cg*8);
      f4 a1 = *(const f4*)(t2 + (size_t)arow*384 + k0 + cg*8 + 4);
      f4 b0 = *(const f4*)(Wo2 + (size_t)brow*384 + k0 + cg*8);
      f4 b1 = *(const f4*)(Wo2 + (size_t)brow*384 + k0 + cg*8 + 4);
      h8 ah, al, bh, bl;
      #pragma unroll
      for (int j = 0; j < 4; ++j){
        ah[j] = (_Float16)a0[j];   al[j] = (_Float16)(a0[j] - (float)ah[j]);
        ah[4+j] = (_Float16)a1[j]; al[4+j] = (_Float16)(a1[j] - (float)ah[4+j]);
        bh[j] = (_Float16)b0[j];   bl[j] = (_Float16)(b0[j] - (float)bh[j]);
        bh[4+j] = (_Float16)b1[j]; bl[4+j] = (_Float16)(b1[j] - (float)bh[4+j]);
      }
      __syncthreads();
      *(h8*)(Ah + r*40 + cg*8) = ah; *(h8*)(Al + r*40 + cg*8) = al;
      *(h8*)(Bh + r*40 + cg*8) = bh; *(h8*)(Bl + r*40 + cg*8) = bl;
      __syncthreads();
      h8 afh = *(const h8*)(Ah + (w*16+col)*40 + quad*8);
      h8 afl = *(const h8*)(Al + (w*16+col)*40 + quad*8);
      #pragma unroll
      for (int nt = 0; nt < 4; ++nt){
        h8 bfh = *(const h8*)(Bh + (nt*16+col)*40 + quad*8);
        h8 bfl = *(const h8*)(Bl + (nt*16+col)*40 + quad*8);
        acc[nt] = mfma16h(afh, bfh, acc[nt]);
        acc[nt] = mfma16h(afl, bfh, acc[nt]);
        acc[nt] = mfma16h(afh, bfl, acc[nt]);
      }
    }
    #pragma unroll
    for (int nt = 0; nt < 4; ++nt){
      #pragma unroll
      for (int rr = 0; rr < 4; ++rr){
        int row = m0 + w*16 + quad*4 + rr;
        int o = n0 + nt*16 + col;
        if (row < 392 && o < 392){
          int g = o / NN, nn = o % NN;
          int b = row / SS, s = row % SS;
          float rng = (g == 0) ? (1.0f/HH) : (1.0f/WW);
          offp[((b*NN + nn)*SS + s)*2 + g] = tanhf(acc[nt][rr]) * rng * 2.0f;
        }
      }
    }
  } else {
    int idx = bid - 49;
    int m0 = (idx % 25)*64, n0 = ((idx/25) % 6)*64, h = idx/150;
    {
      int r = t>>2, cg = t&3;
      int arow = min(m0 + r, NTOK-1);
      f4 a0 = *(const f4*)(qf + (size_t)arow*384 + h*32 + cg*8);
      f4 a1 = *(const f4*)(qf + (size_t)arow*384 + h*32 + cg*8 + 4);
      h8 ah, al;
      #pragma unroll
      for (int j = 0; j < 4; ++j){
        ah[j] = (_Float16)a0[j];   al[j] = (_Float16)(a0[j] - (float)ah[j]);
        ah[4+j] = (_Float16)a1[j]; al[4+j] = (_Float16)(a1[j] - (float)ah[4+j]);
      }
      *(h8*)(Ah + r*40 + cg*8) = ah; *(h8*)(Al + r*40 + cg*8) = al;
    }
    for (int i = t; i < 2048; i += 256){
      int d = i >> 6, c = i & 63;
      float v = Wk[(size_t)(h*32 + d)*384 + n0 + c];
      _Float16 hi = (_Float16)v;
      Bh[c*40 + d] = hi; Bl[c*40 + d] = (_Float16)(v - (float)hi);
    }
    __syncthreads();
    h8 afh = *(const h8*)(Ah + (w*16+col)*40 + quad*8);
    h8 afl = *(const h8*)(Al + (w*16+col)*40 + quad*8);
    f4 acc[4] = {{0,0,0,0},{0,0,0,0},{0,0,0,0},{0,0,0,0}};
    #pragma unroll
    for (int nt = 0; nt < 4; ++nt){
      h8 bfh = *(const h8*)(Bh + (nt*16+col)*40 + quad*8);
      h8 bfl = *(const h8*)(Bl + (nt*16+col)*40 + quad*8);
      acc[nt] = mfma16h(afh, bfh, acc[nt]);
      acc[nt] = mfma16h(afl, bfh, acc[nt]);
      acc[nt] = mfma16h(afh, bfl, acc[nt]);
    }
    #pragma unroll
    for (int nt = 0; nt < 4; ++nt){
      #pragma unroll
      for (int rr = 0; rr < 4; ++rr){
        int m = m0 + w*16 + quad*4 + rr;
        if (m < NTOK)
          qkh[(size_t)m*4608 + h*384 + n0 + nt*16 + col] = (_Float16)acc[nt][rr];
      }
    }
  }
}

// ---------------- fused per-token attention (fp16, 3 blocks/CU) ------------
// LDS 53760B: feats[64][392] fp16 (rows 58-63 multiplexed: biasf f32 [12][58]
// during gather->P2, then attnb fp16 [16][72] + zero tail from P3 on)
__global__ void __launch_bounds__(256, 3) k_fused(
    const float* __restrict__ xh, const float* __restrict__ qf, const float* __restrict__ off,
    const _Float16* __restrict__ qkh,
    const float* __restrict__ bk, const float* __restrict__ Wco, const float* __restrict__ pos,
    _Float16* __restrict__ favh){
  __shared__ _Float16 smem[25088];   // 50176 B
  __shared__ float uni[768];         // qrow|swf|sidx -> scoreS
  __shared__ float offl[98];
  __shared__ float colb[18];
  __shared__ float qbv[12];

  _Float16* feats = smem;
  float*    biasf = (float*)(smem + 58*392);      // [12][58] f32 (2784B of 4704B pad)
  _Float16* attnb = smem + 58*392;                // [16][72] fp16, written in P3
  float* qrow   = uni;
  float* scoreS = uni;
  float* swf    = uni + 384;
  unsigned short* sidx16 = (unsigned short*)(uni + 616);

  int blk = blockIdx.x;
  int n = blk % NN, b = blk / NN;
  int iy = n / WW, ix = n % WW;
  int t = threadIdx.x;
  int w = t>>6, lane = t&63, colh = lane&15, quad = lane>>4;

  // ---- qk prefetch (12 x h8 = 48 VGPRs); lanes 12-15 clamp to head 11 ----
  int hclamp = min(colh, 11);
  const _Float16* qbase = qkh + (size_t)blk*4608 + hclamp*384 + quad*8;
  h8 pf[12];
  #pragma unroll
  for (int kt = 0; kt < 12; ++kt) pf[kt] = *(const h8*)(qbase + kt*32);

  // ---- P0 ----
  for (int c = t; c < 384; c += 256) qrow[c] = qf[(size_t)blk*384 + c];
  for (int i = t; i < 98; i += 256) offl[i] = off[(size_t)blk*98 + i];
  __syncthreads();

  // ---- P1a: colb (co) and qbv[h]=q_h·bk_h ----
  if (t < 144){
    int o = t >> 3, l = t & 7;
    const float* wr = Wco + o*384 + l*48;
    const float* qr = qrow + l*48;
    f4 a4 = {0.f,0.f,0.f,0.f};
    #pragma unroll
    for (int c = 0; c < 48; c += 4) a4 += (*(const f4*)(qr + c)) * (*(const f4*)(wr + c));
    float acc = a4[0]+a4[1]+a4[2]+a4[3];
    acc += __shfl_xor(acc, 1); acc += __shfl_xor(acc, 2); acc += __shfl_xor(acc, 4);
    if (l == 0){
      int g = o & 1;
      float range = (g == 0) ? (1.0f/HH) : (1.0f/WW);
      colb[o] = tanhf(acc) * range;
    }
  }
  if (t >= 160){
    int o = t - 160;
    int h = o >> 3, l = o & 7;
    float acc = 0.f;
    for (int d = l; d < 32; d += 8) acc += qrow[h*32 + d] * bk[h*32 + d];
    acc += __shfl_xor(acc, 1); acc += __shfl_xor(acc, 2); acc += __shfl_xor(acc, 4);
    if (l == 0 && h < 12) qbv[h] = acc;
  }
  __syncthreads();

  // ---- P1-prep: bilinear corner idx/weights ----
  if (t < SK){
    float cy, cx;
    if (t < SS){
      int sy = t / RW, sx = t % RW;
      cy = offl[t*2+0] + ((2.0f*sy)/13.0f*2.0f - 1.0f);
      cx = offl[t*2+1] + ((2.0f*sx)/13.0f*2.0f - 1.0f);
    } else {
      int kk = t - SS;
      float cyr = fminf(fmaxf((float)iy + c_offm[kk][0], 0.f), (float)HH);
      float cxr = fminf(fmaxf((float)ix + c_offm[kk][1], 0.f), (float)WW);
      cy = colb[kk*2+0] + (cyr/13.0f*2.0f - 1.0f);
      cx = colb[kk*2+1] + (cxr/13.0f*2.0f - 1.0f);
    }
    float py = (cy + 1.0f)*0.5f*13.0f;
    float px = (cx + 1.0f)*0.5f*13.0f;
    float y0 = floorf(py), x0 = floorf(px);
    float wy1 = py - y0, wx1 = px - x0;
    #pragma unroll
    for (int k4 = 0; k4 < 4; ++k4){
      float yf = y0 + (k4 >> 1), xf = x0 + (k4 & 1);
      bool valid = (yf >= 0.f) && (yf <= 13.f) && (xf >= 0.f) && (xf <= 13.f);
      int yi = (int)fminf(fmaxf(yf, 0.f), 13.f);
      int xi = (int)fminf(fmaxf(xf, 0.f), 13.f);
      float wgt = ((k4 >> 1) ? wy1 : (1.f - wy1)) * ((k4 & 1) ? wx1 : (1.f - wx1));
      sidx16[t*4 + k4] = (unsigned short)(yi*WW + xi);
      swf[t*4 + k4] = valid ? wgt : 0.f;
    }
  }
  __syncthreads();

  // ---- gather: feats (fp16) + rel-pos bias -> biasf (rows 58-63 region) ----
  {
    const float* xb = xh + (size_t)b*75264;
    for (int i = t; i < 58*96; i += 256){
      int s = i / 96, c4 = (i - s*96)*4;
      const float* sw = swf + s*4;
      const unsigned short* si = sidx16 + s*4;
      f4 v0 = *(const f4*)(xb + si[0]*384 + c4);
      f4 v1 = *(const f4*)(xb + si[1]*384 + c4);
      f4 v2 = *(const f4*)(xb + si[2]*384 + c4);
      f4 v3 = *(const f4*)(xb + si[3]*384 + c4);
      h4 o;
      #pragma unroll
      for (int j = 0; j < 4; ++j)
        o[j] = (_Float16)(v0[j]*sw[0] + v1[j]*sw[1] + v2[j]*sw[2] + v3[j]*sw[3]);
      *(h4*)(feats + s*392 + c4) = o;
    }
    for (int i = t; i < SK*NHEADS; i += 256){
      int s = i / NHEADS, h = i - s*NHEADS;
      float ry, rx;
      if (s < SS){
        int sy = s / RW, sx = s % RW;
        ry = (2.0f*sy - iy)/13.0f - offl[s*2+0];
        rx = (2.0f*sx - ix)/13.0f - offl[s*2+1];
      } else {
        int kk = s - SS;
        ry = colb[kk*2+0] - (float)iy;
        rx = colb[kk*2+1] - (float)ix;
      }
      float py = (ry + 1.0f)*0.5f*26.0f;
      float px = (rx + 1.0f)*0.5f*26.0f;
      float y0 = floorf(py), x0 = floorf(px);
      float wy1 = py - y0, wx1 = px - x0;
      float val = 0.f;
      #pragma unroll
      for (int k4 = 0; k4 < 4; ++k4){
        float yf = y0 + (k4 >> 1), xf = x0 + (k4 & 1);
        if (yf >= 0.f && yf <= 26.f && xf >= 0.f && xf <= 26.f){
          int yi = (int)yf, xi = (int)xf;
          float wgt = ((k4 >> 1) ? wy1 : (1.f - wy1)) * ((k4 & 1) ? wx1 : (1.f - wx1));
          val += pos[(h*TH + yi)*TH + xi] * wgt;
        }
      }
      biasf[h*58 + s] = val + qbv[h];
    }
  }
  __syncthreads();

  // ---- P2: logits D[h][s] = qk·feats (single fp16, 12 MFMAs), C-init=biasf ----
  // (B-fragments for s rows 58-63 read biasf garbage -> D[.][s>=58] discarded in P3)
  {
    f4 acc;
    #pragma unroll
    for (int r = 0; r < 4; ++r){
      int h = quad*4 + r;
      int s = w*16 + colh;
      acc[r] = (h < 12 && s < SK) ? biasf[h*58 + s] : 0.f;
    }
    #pragma unroll
    for (int kt = 0; kt < 12; ++kt){
      h8 bfr = *(const h8*)(feats + (w*16 + colh)*392 + kt*32 + quad*8);
      acc = mfma16h(pf[kt], bfr, acc);
    }
    #pragma unroll
    for (int r = 0; r < 4; ++r){
      int h = quad*4 + r;
      if (h < 12) scoreS[h*64 + w*16 + colh] = acc[r];   // uni dead since gather barrier
    }
  }
  __syncthreads();

  // ---- P3: softmax -> attnb fp16 [16][72] + zero tail (overwrites biasf) ----
  if (t < 192){
    int h = t >> 4, l = t & 15;
    float v[4];
    #pragma unroll
    for (int k = 0; k < 4; ++k){ int s = l + 16*k; v[k] = (s < SK) ? scoreS[h*64 + s] : -1e30f; }
    float mx = fmaxf(fmaxf(v[0], v[1]), fmaxf(v[2], v[3]));
    mx = fmaxf(mx, __shfl_xor(mx, 1)); mx = fmaxf(mx, __shfl_xor(mx, 2));
    mx = fmaxf(mx, __shfl_xor(mx, 4)); mx = fmaxf(mx, __shfl_xor(mx, 8));
    float e[4], sum = 0.f;
    #pragma unroll
    for (int k = 0; k < 4; ++k){ int s = l + 16*k; e[k] = (s < SK) ? expf(v[k] - mx) : 0.f; sum += e[k]; }
    sum += __shfl_xor(sum, 1); sum += __shfl_xor(sum, 2);
    sum += __shfl_xor(sum, 4); sum += __shfl_xor(sum, 8);
    float inv = 1.0f / sum;
    #pragma unroll
    for (int k = 0; k < 4; ++k){
      int s = l + 16*k;
      float p = (s < SK) ? e[k]*inv : 0.f;
      attnb[h*72 + s] = (_Float16)p;
    }
    if (l < 8) attnb[h*72 + 64 + l] = (_Float16)0.f;
  }
  // zero heads 12-15 + remaining pad (indices 864..2351 of the 2352-short region)
  for (int i = 864 + t; i < 2352; i += 256) attnb[i] = (_Float16)0.f;
  __syncthreads();

  // ---- P4: fav[h][c] = sum_s attn[h][s]*feats[s][c]; fp16 out (2 MFMAs) ----
  {
    h8 a0 = *(const h8*)(attnb + colh*72 + quad*8);
    h8 a1 = *(const h8*)(attnb + colh*72 + 32 + quad*8);
    #pragma unroll
    for (int i = 0; i < 6; ++i){
      int c = (w*6 + i)*16 + colh;
      h8 b0, b1;
      #pragma unroll
      for (int j = 0; j < 8; ++j){
        b0[j] = feats[(quad*8 + j)*392 + c];
        b1[j] = feats[(32 + quad*8 + j)*392 + c];
      }
      f4 acc = {0.f,0.f,0.f,0.f};
      acc = mfma16h(a0, b0, acc);
      acc = mfma16h(a1, b1, acc);
      #pragma unroll
      for (int r = 0; r < 4; ++r){
        int h = quad*4 + r;
        if (h < 12) favh[(size_t)blk*4608 + h*384 + c] = (_Float16)acc[r];
      }
    }
  }
}

// ---------------- per-head Wv MFMA GEMM (no LDS): otok = fav_h·Wv_h + bv ----
__global__ void __launch_bounds__(256) k_wv(const _Float16* __restrict__ favh, const float* __restrict__ Wv,
                                            const float* __restrict__ bv, float* __restrict__ otok){
  int t = threadIdx.x;
  int w = t>>6, lane = t&63, col = lane&15, quad = lane>>4;
  int m0 = blockIdx.x*64; int h = blockIdx.y;
  int arow = min(m0 + w*16 + col, NTOK-1);
  f4 acc[2] = {{0,0,0,0},{0,0,0,0}};
  for (int k0 = 0; k0 < 384; k0 += 32){
    h8 af = *(const h8*)(favh + (size_t)arow*4608 + h*384 + k0 + quad*8);
    #pragma unroll
    for (int nt = 0; nt < 2; ++nt){
      int orow = h*32 + nt*16 + col;
      f4 b0 = *(const f4*)(Wv + (size_t)orow*384 + k0 + quad*8);
      f4 b1 = *(const f4*)(Wv + (size_t)orow*384 + k0 + quad*8 + 4);
      h8 bh, bl;
      #pragma unroll
      for (int j = 0; j < 4; ++j){
        bh[j] = (_Float16)b0[j];   bl[j] = (_Float16)(b0[j] - (float)bh[j]);
        bh[4+j] = (_Float16)b1[j]; bl[4+j] = (_Float16)(b1[j] - (float)bh[4+j]);
      }
      acc[nt] = mfma16h(af, bh, acc[nt]);
      acc[nt] = mfma16h(af, bl, acc[nt]);
    }
  }
  #pragma unroll
  for (int nt = 0; nt < 2; ++nt){
    #pragma unroll
    for (int rr = 0; rr < 4; ++rr){
      int m = m0 + w*16 + quad*4 + rr;
      if (m < NTOK){
        int o = h*32 + nt*16 + col;
        otok[(size_t)m*384 + o] = acc[nt][rr] + bv[o];
      }
    }
  }
}

extern "C" void kernel_launch(void* const* d_in, const int* in_sizes, int n_in,
                              void* d_out, int out_size, void* d_ws, size_t ws_size,
                              hipStream_t stream){
  const float* x    = (const float*)d_in[0];
  const float* Wq   = (const float*)d_in[1];
  const float* bq   = (const float*)d_in[2];
  const float* Wk   = (const float*)d_in[3];
  const float* bk   = (const float*)d_in[4];
  const float* Wv   = (const float*)d_in[5];
  const float* bv   = (const float*)d_in[6];
  const float* Wo1  = (const float*)d_in[7];
  const float* bo1  = (const float*)d_in[8];
  const float* Wdw  = (const float*)d_in[9];
  const float* bdw  = (const float*)d_in[10];
  const float* ln_g = (const float*)d_in[11];
  const float* ln_b = (const float*)d_in[12];
  const float* Wo2  = (const float*)d_in[13];
  const float* Wco  = (const float*)d_in[14];
  const float* pos  = (const float*)d_in[15];
  const float* Wp   = (const float*)d_in[16];
  const float* bp   = (const float*)d_in[17];
  float* out = (float*)d_out;

  float* ws   = (float*)d_ws;
  float* xh   = ws;
  float* qf   = xh   + 602112;
  float* t1   = qf   + 602112;
  float* t2   = t1   + 602112;
  float* offp = t2   + 150528;
  float* otok = offp + 153664;
  _Float16* qkh  = (_Float16*)(otok + 602112);   // 1568*4608 fp16 (~14.45 MB)
  _Float16* favh = qkh;   // same-token alias: P2 prefetches blk's qk before P4 writes blk's fav

  k_transpose2<<<64, 256, 0, stream>>>(x, xh);
  k_mmf<0><<<dim3(25,6), 256, 0, stream>>>(xh, Wq,  bq,  qf, NTOK, 384);
  k_mmf<1><<<dim3(25,6), 256, 0, stream>>>(qf, Wo1, bo1, t1, NTOK, 384);
  k_dwln<<<392, 384, 0, stream>>>(t1, Wdw, bdw, ln_g, ln_b, t2);
  k_offqk<<<1849, 256, 0, stream>>>(t2, Wo2, offp, qf, Wk, qkh);
  k_fused<<<1568, 256, 0, stream>>>(xh, qf, offp, qkh, bk, Wco, pos, favh);
  k_wv<<<dim3(25,12), 256, 0, stream>>>(favh, Wv, bv, otok);
  k_mmf<2><<<dim3(25,6), 256, 0, stream>>>(otok, Wp, bp, out, NTOK, 384);
}